// Round 20
// baseline (1421.375 us; speedup 1.0000x reference)
//
#include <hip/hip_runtime.h>
#include <hip/hip_bf16.h>

#define N_NODES 131072
#define N_EDGES 524288
#define F_IN 16
#define DIM 64
#define DNN 16
#define BK 4
#define NG 8192
#define N_ITERS 8   // NL1*NL2

typedef __bf16 bf16x8 __attribute__((ext_vector_type(8)));
typedef __bf16 bf16x4 __attribute__((ext_vector_type(4)));
typedef float f32x4 __attribute__((ext_vector_type(4)));

#define FMA4(A_, S_, W_) { (A_).x = fmaf((S_), (W_).x, (A_).x); (A_).y = fmaf((S_), (W_).y, (A_).y); \
                           (A_).z = fmaf((S_), (W_).z, (A_).z); (A_).w = fmaf((S_), (W_).w, (A_).w); }

__device__ __forceinline__ unsigned bf16_rne(float f) {
    unsigned u = __float_as_uint(f);
    return (u + 0x7fffu + ((u >> 16) & 1u)) >> 16;
}

// ---------------- degree (int, node-indexed) ----------------
__global__ __launch_bounds__(256) void k_degree(const int* __restrict__ ei, int* __restrict__ cnt) {
    int e = blockIdx.x * 256 + threadIdx.x;
    atomicAdd(&cnt[ei[N_EDGES + e]], 1);
}

// ---------------- degree-descending counting sort: hist -> offsets -> slot_of ----------------
__global__ __launch_bounds__(256) void k_hist(const int* __restrict__ cnt, int* __restrict__ hist) {
    int n = blockIdx.x * 256 + threadIdx.x;
    int key = 31 - min(cnt[n], 31);            // slot ascending == degree descending
    atomicAdd(&hist[key], 1);
}

__global__ __launch_bounds__(64) void k_binoff(const int* __restrict__ hist, int* __restrict__ binoff) {
    if (threadIdx.x == 0) {
        int acc = 0;
#pragma unroll
        for (int i = 0; i < 32; ++i) { binoff[i] = acc; acc += hist[i]; }
    }
}

// slot_of[node]; per-slot arrays: cnts, invs, batchs
__global__ __launch_bounds__(256) void k_permute(const int* __restrict__ cnt, const int* __restrict__ binoff,
                                                 int* __restrict__ bincur, const int* __restrict__ batch,
                                                 int* __restrict__ slot_of, int* __restrict__ cnts,
                                                 float* __restrict__ invs, int* __restrict__ batchs) {
    int n = blockIdx.x * 256 + threadIdx.x;
    int deg = cnt[n];
    int key = 31 - min(deg, 31);
    int slot = binoff[key] + atomicAdd(&bincur[key], 1);
    slot_of[n] = slot;
    cnts[slot] = deg;
    invs[slot] = 1.0f / (float)max(deg, 1);
    batchs[slot] = batch[n];
}

// ---------------- CSR scan (slot-indexed) ----------------
__global__ __launch_bounds__(256) void k_scanA(const int* __restrict__ cnt, int* __restrict__ excl,
                                               int* __restrict__ bsum) {
    __shared__ int a[256], b[256];
    int t = threadIdx.x, gid = blockIdx.x * 256 + t;
    int c = cnt[gid];
    a[t] = c; __syncthreads();
    int *s = a, *d = b;
#pragma unroll
    for (int off = 1; off < 256; off <<= 1) {
        d[t] = s[t] + (t >= off ? s[t - off] : 0);
        __syncthreads();
        int* tmp = s; s = d; d = tmp;
    }
    excl[gid] = s[t] - c;
    if (t == 255) bsum[blockIdx.x] = s[255];
}

__global__ __launch_bounds__(256) void k_scanB(const int* __restrict__ bsum, int* __restrict__ boff) {
    __shared__ int a[512], b[512];
    int t = threadIdx.x;
    a[t] = bsum[t]; a[t + 256] = bsum[t + 256];
    __syncthreads();
    int *s = a, *d = b;
#pragma unroll
    for (int off = 1; off < 512; off <<= 1) {
        d[t] = s[t] + (t >= off ? s[t - off] : 0);
        int i2 = t + 256;
        d[i2] = s[i2] + (i2 >= off ? s[i2 - off] : 0);
        __syncthreads();
        int* tmp = s; s = d; d = tmp;
    }
    boff[t] = t ? s[t - 1] : 0;
    boff[t + 256] = s[t + 255];
}

__global__ __launch_bounds__(256) void k_scanC(const int* __restrict__ excl, const int* __restrict__ boff,
                                               int* __restrict__ row_ptr, int* __restrict__ cursor) {
    int gid = blockIdx.x * 256 + threadIdx.x;
    int v = excl[gid] + boff[gid >> 8];
    row_ptr[gid] = v;
    cursor[gid] = v;
    if (gid == 0) row_ptr[N_NODES] = N_EDGES;
}

// packed edge record (slot space): {src_slot, bf16(a0,a1), bf16(a2,a3), 0}
__global__ __launch_bounds__(256) void k_scatter(const int* __restrict__ ei, const float* __restrict__ ea,
                                                 const int* __restrict__ slot_of,
                                                 int* __restrict__ cursor, int4* __restrict__ csr_pk) {
    int e = blockIdx.x * 256 + threadIdx.x;
    int ds = slot_of[ei[N_EDGES + e]];
    int pos = atomicAdd(&cursor[ds], 1);
    float4 a = ((const float4*)ea)[e];
    unsigned a01 = bf16_rne(a.x) | (bf16_rne(a.y) << 16);
    unsigned a23 = bf16_rne(a.z) | (bf16_rne(a.w) << 16);
    csr_pk[pos] = make_int4(slot_of[ei[e]], (int)a01, (int)a23, 0);
}

// ---------------- prep: bf16 B-fragment weight tiles ----------------
#define WB_SZ (4 * 40 * 512)
__global__ __launch_bounds__(256) void k_prep(const float* __restrict__ wih, const float* __restrict__ whh,
                                              const float* __restrict__ rw, const float* __restrict__ w1,
                                              const float* __restrict__ bih, const float* __restrict__ bhh,
                                              const float* __restrict__ nn1w, const float* __restrict__ nn1b,
                                              __bf16* __restrict__ Wb, __bf16* __restrict__ B2b,
                                              __bf16* __restrict__ w1b) {
    int idx = blockIdx.x * 256 + threadIdx.x;
    if (idx < WB_SZ) {
        int j = idx / 20480, r = idx % 20480;
        int t = r >> 9, e = r & 511;
        int jj = e & 7, c16 = (e >> 3) & 15, kq = e >> 7;
        int ct, kk; bool nih = false;
        if (t < 36) { ct = t / 3; kk = t % 3; } else { ct = 8 + (t - 36); kk = 0; nih = true; }
        int k = kk * 32 + kq * 8 + jj;
        int c = ct * 16 + c16;
        bool ngate = ct >= 8;
        float v = 0.f;
        if (nih) {
            if (k < 16) v = wih[((size_t)j * 192 + c) * 16 + k];
        } else {
            if (k < 16) v = ngate ? 0.f : wih[((size_t)j * 192 + c) * 16 + k];
            else if (k < 80) v = whh[((size_t)j * 192 + c) * 64 + (k - 16)];
            else if (k == 80) v = ngate ? bhh[j * 192 + c] : (bih[j * 192 + c] + bhh[j * 192 + c]);
        }
        Wb[idx] = (__bf16)v;
    } else if (idx < WB_SZ + 1536) {
        int e = idx - WB_SZ;
        int t = e >> 9, ee = e & 511;
        int jj = ee & 7, c16 = (ee >> 3) & 15, kq = ee >> 7;
        int krow = t * 32 + kq * 8 + jj;
        float v;
        if (krow < 16) v = rw[krow * 16 + c16];
        else {
            int i = (krow - 16) >> 4, kk = (krow - 16) & 15;
            v = (i == 0) ? nn1b[kk * 16 + c16] : nn1w[(i - 1) * 256 + kk * 16 + c16];
        }
        B2b[e] = (__bf16)v;
    } else if (idx < WB_SZ + 1536 + 1024) {
        int e = idx - (WB_SZ + 1536);
        int t2 = e >> 9, ee = e & 511;
        int jj = ee & 7, c16 = (ee >> 3) & 15, kq = ee >> 7;
        int k = t2 * 32 + kq * 8 + jj;
        w1b[e] = (__bf16)w1[k * 16 + c16];
    }
}

// ---------------- init: h[slot] = relu(x[node] @ lin0_w + lin0_b) -> bf16 ----------------
__global__ __launch_bounds__(256) void k_init(const float* __restrict__ x, const float* __restrict__ w,
                                              const float* __restrict__ b, const int* __restrict__ slot_of,
                                              __bf16* __restrict__ h) {
    __shared__ float s_w[F_IN * DIM];
    int tid = threadIdx.x;
    for (int i = tid; i < F_IN * DIM; i += 256) s_w[i] = w[i];
    int node = blockIdx.x * 16 + (tid >> 4);
    int c4 = tid & 15;
    const float4* xp = (const float4*)(x + (size_t)node * F_IN);
    float4 x0 = xp[0], x1 = xp[1], x2 = xp[2], x3 = xp[3];
    float xa[16] = {x0.x, x0.y, x0.z, x0.w, x1.x, x1.y, x1.z, x1.w,
                    x2.x, x2.y, x2.z, x2.w, x3.x, x3.y, x3.z, x3.w};
    __syncthreads();
    float4 acc = ((const float4*)b)[c4];
    const float4* w4 = (const float4*)s_w;
#pragma unroll
    for (int k = 0; k < 16; ++k) {
        float4 wv = w4[k * 16 + c4];
        FMA4(acc, xa[k], wv);
    }
    bf16x4 hv;
    hv[0] = (__bf16)fmaxf(acc.x, 0.f); hv[1] = (__bf16)fmaxf(acc.y, 0.f);
    hv[2] = (__bf16)fmaxf(acc.z, 0.f); hv[3] = (__bf16)fmaxf(acc.w, 0.f);
    int s = slot_of[node];
    *(bf16x4*)&h[(size_t)s * DIM + c4 * 4] = hv;
}

// ---------------- out1 = h @ lin1_w + lin1_b (slot space; bf16 in/out) ----------------
__global__ __launch_bounds__(256) void k_lin1(const __bf16* __restrict__ h, const float* __restrict__ w,
                                              const float* __restrict__ b, __bf16* __restrict__ out1) {
    __shared__ float s_h[64 * 68];
    int tid = threadIdx.x;
    int nb = blockIdx.x * 64;
    for (int i = tid; i < 64 * 16; i += 256) {
        int n = i >> 4, q4 = i & 15;
        bf16x4 v = *(const bf16x4*)&h[(size_t)(nb + n) * 64 + q4 * 4];
        float* d = &s_h[n * 68 + q4 * 4];
        d[0] = (float)v[0]; d[1] = (float)v[1]; d[2] = (float)v[2]; d[3] = (float)v[3];
    }
    int ct = tid & 15;
    float wcol[64];
#pragma unroll
    for (int q = 0; q < 64; ++q) wcol[q] = w[q * 16 + ct];
    float bias = b[ct];
    __syncthreads();
    int ng = tid >> 4;
#pragma unroll
    for (int rep = 0; rep < 4; ++rep) {
        int nl = ng + 16 * rep;
        float acc = bias;
#pragma unroll
        for (int q4 = 0; q4 < 16; ++q4) {
            float4 hv = *(const float4*)&s_h[nl * 68 + q4 * 4];
            acc = fmaf(hv.x, wcol[4 * q4 + 0], acc);
            acc = fmaf(hv.y, wcol[4 * q4 + 1], acc);
            acc = fmaf(hv.z, wcol[4 * q4 + 2], acc);
            acc = fmaf(hv.w, wcol[4 * q4 + 3], acc);
        }
        out1[(size_t)(nb + nl) * 16 + ct] = (__bf16)acc;
    }
}

// ---------------- node v14: degree-sorted slots + packed gather + MFMA GRU ----------------
// All node state is in degree-descending slot order: a wave's 16 slots have
// near-equal degree -> gather rounds ~= degree (was max-of-16 ~10); heavy
// blocks dispatch first (LPT) so the drain tail shrinks.
__attribute__((amdgpu_waves_per_eu(2, 4)))
__global__ __launch_bounds__(512) void k_node(
    const __bf16* __restrict__ out1_in, __bf16* __restrict__ out1_out,
    const int4* __restrict__ csr_pk,
    const int* __restrict__ row_ptr, const float* __restrict__ invs,
    __bf16* __restrict__ h, const __bf16* __restrict__ Wb, const __bf16* __restrict__ B2b,
    const __bf16* __restrict__ w1b, const float* __restrict__ conv_b,
    const float* __restrict__ bih, const float* __restrict__ lin1_b,
    const int* __restrict__ batchs, const float* __restrict__ lin2_w,
    float* __restrict__ out, int do_final)
{
    __shared__ __align__(16) __bf16 s_X[128 * 104];  // 26624 B
    __shared__ __align__(16) __bf16 s_W[40 * 512];   // 40960 B
    __shared__ __align__(16) __bf16 s_B2[3 * 512];   //  3072 B
    __shared__ __align__(16) __bf16 s_w1[1024];      //  2048 B  (total 72704)
    int tid = threadIdx.x;
    int nb = blockIdx.x * 128;
    int lane = tid & 63, w = tid >> 6;               // w = 0..7
    int c16 = lane & 15, lq = lane >> 4;
    int nwb = nb + w * 16;
    int xrow = w * 16;

    // cooperative staging of weight tiles (512 threads)
    {
        const float4* src = (const float4*)Wb;
        float4* dst = (float4*)s_W;
#pragma unroll
        for (int i = 0; i < 5; ++i) dst[tid + 512 * i] = src[tid + 512 * i];
        if (tid < 192) ((float4*)s_B2)[tid] = ((const float4*)B2b)[tid];
        else if (tid < 320) ((float4*)s_w1)[tid - 192] = ((const float4*)w1b)[tid - 192];
    }
    // own out1 row -> X2[.][0..15]  (wave-private rows)
    {
        int n = lane >> 2, k4 = lane & 3;
        bf16x4 v = *(const bf16x4*)&out1_in[(size_t)(nwb + n) * 16 + k4 * 4];
        *(bf16x4*)&s_X[(xrow + n) * 104 + k4 * 4] = v;
    }
    __syncthreads();   // the ONLY block-wide barrier (covers s_W/s_B2/s_w1)

    // gather: wave-private. group gi = lane>>4 handles slots nwb + gi*4 + r (r=0..3)
    {
        int gi = lane >> 4, k = lane & 15;
        int e0[4], dr[4];
        int4 pk[4];
        float S0[4] = {0.f,0.f,0.f,0.f}, S1[4] = {0.f,0.f,0.f,0.f}, S2[4] = {0.f,0.f,0.f,0.f},
              S3[4] = {0.f,0.f,0.f,0.f}, S4[4] = {0.f,0.f,0.f,0.f};
        int rounds = 0;
#pragma unroll
        for (int r = 0; r < 4; ++r) {
            int n = nwb + gi * 4 + r;
            e0[r] = row_ptr[n];
            dr[r] = row_ptr[n + 1] - e0[r];
            rounds = max(rounds, dr[r]);
            pk[r] = csr_pk[min(e0[r], N_EDGES - 1)];
        }
        for (int t = 0; t < rounds; ++t) {
            int4 pkn[4]; float xv[4];
#pragma unroll
            for (int r = 0; r < 4; ++r)
                pkn[r] = csr_pk[min(e0[r] + t + 1, N_EDGES - 1)];
#pragma unroll
            for (int r = 0; r < 4; ++r)
                xv[r] = (float)out1_in[(size_t)(pk[r].x & 0xFFFFF) * 16 + k];
#pragma unroll
            for (int r = 0; r < 4; ++r) {
                float xm = (t < dr[r]) ? xv[r] : 0.0f;
                float a0 = __uint_as_float(((unsigned)pk[r].y) << 16);
                float a1 = __uint_as_float(((unsigned)pk[r].y) & 0xffff0000u);
                float a2 = __uint_as_float(((unsigned)pk[r].z) << 16);
                float a3 = __uint_as_float(((unsigned)pk[r].z) & 0xffff0000u);
                S0[r] += xm;
                S1[r] = fmaf(a0, xm, S1[r]);
                S2[r] = fmaf(a1, xm, S2[r]);
                S3[r] = fmaf(a2, xm, S3[r]);
                S4[r] = fmaf(a3, xm, S4[r]);
                pk[r] = pkn[r];
            }
        }
#pragma unroll
        for (int r = 0; r < 4; ++r) {
            int nl = xrow + gi * 4 + r;
            float inv = invs[nwb + gi * 4 + r];
            __bf16* p = &s_X[nl * 104];
            p[16 + k] = (__bf16)(S0[r] * inv);
            p[32 + k] = (__bf16)(S1[r] * inv);
            p[48 + k] = (__bf16)(S2[r] * inv);
            p[64 + k] = (__bf16)(S3[r] * inv);
            p[80 + k] = (__bf16)(S4[r] * inv);
        }
    }
    // no barrier: s_X rows are wave-private; same-wave DS ops are in program order

    // phase 2: o2 = X2 @ B2 + conv_b (K=96)
    float cb = conv_b[c16];
    f32x4 co2 = (f32x4){cb, cb, cb, cb};
#pragma unroll
    for (int kk = 0; kk < 3; ++kk) {
        bf16x8 a = *(const bf16x8*)&s_X[(xrow + c16) * 104 + kk * 32 + lq * 8];
        bf16x8 b = *(const bf16x8*)&s_B2[kk * 512 + lane * 8];
        co2 = __builtin_amdgcn_mfma_f32_16x16x32_bf16(a, b, co2, 0, 0, 0);
    }

    // phase 3a: rebuild X = [o2(16) | h(64) | 1 | 0..]  (wave-own rows)
#pragma unroll
    for (int jr = 0; jr < 4; ++jr)
        s_X[(xrow + 4 * lq + jr) * 104 + c16] = (__bf16)co2[jr];
    {
        const bf16x8* hsrc = (const bf16x8*)(h + (size_t)nwb * 64);
#pragma unroll
        for (int ii = 0; ii < 2; ++ii) {
            int idx = lane + 64 * ii;
            int n = idx >> 3, d8 = idx & 7;
            bf16x8 v = hsrc[idx];
            *(bf16x8*)&s_X[(xrow + n) * 104 + 16 + d8 * 8] = v;
        }
    }
    {
        int n = lane >> 2, c0 = 80 + (lane & 3) * 4;
#pragma unroll
        for (int q = 0; q < 4; ++q)
            s_X[(xrow + n) * 104 + c0 + q] = (c0 + q == 80) ? (__bf16)1.0f : (__bf16)0.0f;
    }

    // phase 3b: gates GEMM
    f32x4 acc[12], ani4[4];
#pragma unroll
    for (int i = 0; i < 12; ++i) acc[i] = (f32x4){0.f, 0.f, 0.f, 0.f};
#pragma unroll
    for (int i = 0; i < 4; ++i) ani4[i] = (f32x4){0.f, 0.f, 0.f, 0.f};
    bf16x8 af[3];
#pragma unroll
    for (int kk = 0; kk < 3; ++kk)
        af[kk] = *(const bf16x8*)&s_X[(xrow + c16) * 104 + kk * 32 + lq * 8];
#pragma unroll
    for (int ct = 0; ct < 12; ++ct) {
#pragma unroll
        for (int kk = 0; kk < 3; ++kk) {
            bf16x8 bf = *(const bf16x8*)&s_W[(ct * 3 + kk) * 512 + lane * 8];
            acc[ct] = __builtin_amdgcn_mfma_f32_16x16x32_bf16(af[kk], bf, acc[ct], 0, 0, 0);
        }
    }
#pragma unroll
    for (int ct8 = 0; ct8 < 4; ++ct8) {
        bf16x8 bf = *(const bf16x8*)&s_W[(36 + ct8) * 512 + lane * 8];
        ani4[ct8] = __builtin_amdgcn_mfma_f32_16x16x32_bf16(af[0], bf, ani4[ct8], 0, 0, 0);
    }

    // GRU epilogue (hold from s_X bf16); keep h_new in registers
    float hn[4][4];
#pragma unroll
    for (int ct = 0; ct < 4; ++ct) {
        float bni = bih[128 + ct * 16 + c16];
#pragma unroll
        for (int jr = 0; jr < 4; ++jr) {
            float hold = (float)s_X[(xrow + 4 * lq + jr) * 104 + 16 + ct * 16 + c16];
            float rr = 1.f / (1.f + __expf(-acc[ct][jr]));
            float zz = 1.f / (1.f + __expf(-acc[4 + ct][jr]));
            float xx = fmaf(rr, acc[8 + ct][jr], ani4[ct][jr] + bni);
            float ax = fabsf(xx);
            float ee = __expf(-2.f * ax);
            float ncv = __builtin_copysignf((1.f - ee) / (1.f + ee), xx);
            hn[ct][jr] = fmaf(zz, hold - ncv, ncv);
        }
    }
    // write h_new into s_X (same-wave DS order), then coalesced bf16 writeback to h
#pragma unroll
    for (int ct = 0; ct < 4; ++ct)
#pragma unroll
        for (int jr = 0; jr < 4; ++jr)
            s_X[(xrow + 4 * lq + jr) * 104 + 16 + ct * 16 + c16] = (__bf16)hn[ct][jr];
    {
        bf16x8* hdst = (bf16x8*)(h + (size_t)nwb * 64);
#pragma unroll
        for (int ii = 0; ii < 2; ++ii) {
            int idx = lane + 64 * ii;
            int n = idx >> 3, d8 = idx & 7;
            bf16x8 v = *(const bf16x8*)&s_X[(xrow + n) * 104 + 16 + d8 * 8];
            hdst[idx] = v;
        }
    }

    if (!do_final) {
        // fused lin1 -> out1_out (bf16)
        f32x4 o1acc = (f32x4){0.f, 0.f, 0.f, 0.f};
#pragma unroll
        for (int kk = 0; kk < 2; ++kk) {
            bf16x8 a = *(const bf16x8*)&s_X[(xrow + c16) * 104 + 16 + kk * 32 + lq * 8];
            bf16x8 b = *(const bf16x8*)&s_w1[kk * 512 + lane * 8];
            o1acc = __builtin_amdgcn_mfma_f32_16x16x32_bf16(a, b, o1acc, 0, 0, 0);
        }
        float lb = lin1_b[c16];
#pragma unroll
        for (int jr = 0; jr < 4; ++jr) {
            int node = nwb + 4 * lq + jr;
            out1_out[(size_t)node * 16 + c16] = (__bf16)(o1acc[jr] + lb);
        }
    } else {
        // fused final: y = h_new @ lin2_w ; atomicAdd into out[batchs]
        float w2v[4];
#pragma unroll
        for (int ct = 0; ct < 4; ++ct) w2v[ct] = lin2_w[ct * 16 + c16];
#pragma unroll
        for (int jr = 0; jr < 4; ++jr) {
            float part = hn[0][jr] * w2v[0];
            part = fmaf(hn[1][jr], w2v[1], part);
            part = fmaf(hn[2][jr], w2v[2], part);
            part = fmaf(hn[3][jr], w2v[3], part);
#pragma unroll
            for (int off = 8; off > 0; off >>= 1) part += __shfl_xor(part, off, 64);
            if (c16 == 0) {
                int node = nwb + 4 * lq + jr;
                atomicAdd(&out[batchs[node]], part);
            }
        }
    }
}

extern "C" void kernel_launch(void* const* d_in, const int* in_sizes, int n_in,
                              void* d_out, int out_size, void* d_ws, size_t ws_size,
                              hipStream_t stream) {
    const float* x        = (const float*)d_in[0];
    const float* edge_attr= (const float*)d_in[1];
    const float* lin0_w   = (const float*)d_in[2];
    const float* lin0_b   = (const float*)d_in[3];
    const float* nn1_w    = (const float*)d_in[4];
    const float* nn1_b    = (const float*)d_in[5];
    const float* root_w   = (const float*)d_in[6];
    const float* conv_b   = (const float*)d_in[7];
    const float* gru_w_ih = (const float*)d_in[8];
    const float* gru_w_hh = (const float*)d_in[9];
    const float* gru_b_ih = (const float*)d_in[10];
    const float* gru_b_hh = (const float*)d_in[11];
    const float* lin1_w   = (const float*)d_in[12];
    const float* lin1_b   = (const float*)d_in[13];
    const float* lin2_w   = (const float*)d_in[14];
    const int*   ei       = (const int*)d_in[15];
    const int*   batch    = (const int*)d_in[16];
    float* out = (float*)d_out;

    char* p = (char*)d_ws;
    __bf16* h       = (__bf16*)p;           p += (size_t)N_NODES * DIM * 2;
    __bf16* out1A   = (__bf16*)p;           p += (size_t)N_NODES * DNN * 2;
    __bf16* out1B   = (__bf16*)p;           p += (size_t)N_NODES * DNN * 2;
    int4*   csr_pk  = (int4*)p;             p += (size_t)N_EDGES * 16;
    __bf16* Wb      = (__bf16*)p;           p += (size_t)WB_SZ * 2;
    __bf16* B2b     = (__bf16*)p;           p += 1536 * 2;
    __bf16* w1b     = (__bf16*)p;           p += 1024 * 2;
    int*    cnt     = (int*)p;              p += (size_t)N_NODES * 4;
    float*  invs    = (float*)p;            p += (size_t)N_NODES * 4;
    int*    row_ptr = (int*)p;              p += (size_t)(N_NODES + 16) * 4;
    int*    cursor  = (int*)p;              p += (size_t)N_NODES * 4;
    int*    excl    = (int*)p;              p += (size_t)N_NODES * 4;
    int*    bsum    = (int*)p;              p += 512 * 4;
    int*    boff    = (int*)p;              p += 512 * 4;
    int*    slot_of = (int*)p;              p += (size_t)N_NODES * 4;
    int*    cnts    = (int*)p;              p += (size_t)N_NODES * 4;
    int*    batchs  = (int*)p;              p += (size_t)N_NODES * 4;
    int*    hist    = (int*)p;              p += 32 * 4;
    int*    binoff  = (int*)p;              p += 32 * 4;
    int*    bincur  = (int*)p;              p += 32 * 4;

    hipMemsetAsync(d_out, 0, (size_t)NG * 4, stream);
    hipMemsetAsync(cnt, 0, (size_t)N_NODES * 4, stream);
    hipMemsetAsync(hist, 0, 32 * 4, stream);
    hipMemsetAsync(bincur, 0, 32 * 4, stream);
    k_prep<<<330, 256, 0, stream>>>(gru_w_ih, gru_w_hh, root_w, lin1_w, gru_b_ih, gru_b_hh,
                                    nn1_w, nn1_b, Wb, B2b, w1b);
    k_degree<<<N_EDGES / 256, 256, 0, stream>>>(ei, cnt);
    k_hist<<<N_NODES / 256, 256, 0, stream>>>(cnt, hist);
    k_binoff<<<1, 64, 0, stream>>>(hist, binoff);
    k_permute<<<N_NODES / 256, 256, 0, stream>>>(cnt, binoff, bincur, batch,
                                                 slot_of, cnts, invs, batchs);
    k_scanA<<<N_NODES / 256, 256, 0, stream>>>(cnts, excl, bsum);
    k_scanB<<<1, 256, 0, stream>>>(bsum, boff);
    k_scanC<<<N_NODES / 256, 256, 0, stream>>>(excl, boff, row_ptr, cursor);
    k_scatter<<<N_EDGES / 256, 256, 0, stream>>>(ei, edge_attr, slot_of, cursor, csr_pk);
    k_init<<<N_NODES / 16, 256, 0, stream>>>(x, lin0_w, lin0_b, slot_of, h);
    k_lin1<<<N_NODES / 64, 256, 0, stream>>>(h, lin1_w, lin1_b, out1A);

    for (int it = 0; it < N_ITERS; ++it) {
        int j = it >> 1;   // GRU index (NL2 = 2)
        const __bf16* o_in = (it & 1) ? out1B : out1A;
        __bf16*       o_out= (it & 1) ? out1A : out1B;
        k_node<<<N_NODES / 128, 512, 0, stream>>>(o_in, o_out, csr_pk, row_ptr, invs,
                                                  h, Wb + (size_t)j * 40 * 512, B2b, w1b,
                                                  conv_b, gru_b_ih + (size_t)j * 192, lin1_b,
                                                  batchs, lin2_w, out, it == N_ITERS - 1 ? 1 : 0);
    }
}

// Round 21
// 367.594 us; speedup vs baseline: 3.8667x; 3.8667x over previous
//
#include <hip/hip_runtime.h>
#include <hip/hip_bf16.h>

#define N_NODES 131072
#define N_EDGES 524288
#define F_IN 16
#define DIM 64
#define DNN 16
#define BK 4
#define NG 8192
#define N_ITERS 8   // NL1*NL2

typedef __bf16 bf16x8 __attribute__((ext_vector_type(8)));
typedef __bf16 bf16x4 __attribute__((ext_vector_type(4)));
typedef float f32x4 __attribute__((ext_vector_type(4)));

#define FMA4(A_, S_, W_) { (A_).x = fmaf((S_), (W_).x, (A_).x); (A_).y = fmaf((S_), (W_).y, (A_).y); \
                           (A_).z = fmaf((S_), (W_).z, (A_).z); (A_).w = fmaf((S_), (W_).w, (A_).w); }

__device__ __forceinline__ unsigned bf16_rne(float f) {
    unsigned u = __float_as_uint(f);
    return (u + 0x7fffu + ((u >> 16) & 1u)) >> 16;
}

// ---------------- degree (int, node-indexed) ----------------
__global__ __launch_bounds__(256) void k_degree(const int* __restrict__ ei, int* __restrict__ cnt) {
    int e = blockIdx.x * 256 + threadIdx.x;
    atomicAdd(&cnt[ei[N_EDGES + e]], 1);
}

// ---------------- degree-descending counting sort (two-level histogram) ----------------
// R20 bug: 131072 global atomics onto 32 addresses = 530us. Fix: per-block LDS
// histogram + ONE global atomic per (block,bin).
__global__ __launch_bounds__(256) void k_hist(const int* __restrict__ cnt, int* __restrict__ hist) {
    __shared__ int lh[32];
    int tid = threadIdx.x;
    if (tid < 32) lh[tid] = 0;
    __syncthreads();
    int n = blockIdx.x * 256 + tid;
    int key = 31 - min(cnt[n], 31);            // slot ascending == degree descending
    atomicAdd(&lh[key], 1);
    __syncthreads();
    if (tid < 32 && lh[tid]) atomicAdd(&hist[tid], lh[tid]);
}

__global__ __launch_bounds__(64) void k_binoff(const int* __restrict__ hist, int* __restrict__ binoff) {
    if (threadIdx.x == 0) {
        int acc = 0;
#pragma unroll
        for (int i = 0; i < 32; ++i) { binoff[i] = acc; acc += hist[i]; }
    }
}

// slot_of[node]; per-slot arrays: cnts, invs, batchs
__global__ __launch_bounds__(256) void k_permute(const int* __restrict__ cnt, const int* __restrict__ binoff,
                                                 int* __restrict__ bincur, const int* __restrict__ batch,
                                                 int* __restrict__ slot_of, int* __restrict__ cnts,
                                                 float* __restrict__ invs, int* __restrict__ batchs) {
    __shared__ int lh[32], lbase[32];
    int tid = threadIdx.x;
    if (tid < 32) lh[tid] = 0;
    __syncthreads();
    int n = blockIdx.x * 256 + tid;
    int deg = cnt[n];
    int key = 31 - min(deg, 31);
    int myrank = atomicAdd(&lh[key], 1);       // LDS atomic: block-local rank
    __syncthreads();
    if (tid < 32) lbase[tid] = lh[tid] ? atomicAdd(&bincur[tid], lh[tid]) : 0;
    __syncthreads();
    int slot = binoff[key] + lbase[key] + myrank;
    slot_of[n] = slot;
    cnts[slot] = deg;
    invs[slot] = 1.0f / (float)max(deg, 1);
    batchs[slot] = batch[n];
}

// ---------------- CSR scan (slot-indexed) ----------------
__global__ __launch_bounds__(256) void k_scanA(const int* __restrict__ cnt, int* __restrict__ excl,
                                               int* __restrict__ bsum) {
    __shared__ int a[256], b[256];
    int t = threadIdx.x, gid = blockIdx.x * 256 + t;
    int c = cnt[gid];
    a[t] = c; __syncthreads();
    int *s = a, *d = b;
#pragma unroll
    for (int off = 1; off < 256; off <<= 1) {
        d[t] = s[t] + (t >= off ? s[t - off] : 0);
        __syncthreads();
        int* tmp = s; s = d; d = tmp;
    }
    excl[gid] = s[t] - c;
    if (t == 255) bsum[blockIdx.x] = s[255];
}

__global__ __launch_bounds__(256) void k_scanB(const int* __restrict__ bsum, int* __restrict__ boff) {
    __shared__ int a[512], b[512];
    int t = threadIdx.x;
    a[t] = bsum[t]; a[t + 256] = bsum[t + 256];
    __syncthreads();
    int *s = a, *d = b;
#pragma unroll
    for (int off = 1; off < 512; off <<= 1) {
        d[t] = s[t] + (t >= off ? s[t - off] : 0);
        int i2 = t + 256;
        d[i2] = s[i2] + (i2 >= off ? s[i2 - off] : 0);
        __syncthreads();
        int* tmp = s; s = d; d = tmp;
    }
    boff[t] = t ? s[t - 1] : 0;
    boff[t + 256] = s[t + 255];
}

__global__ __launch_bounds__(256) void k_scanC(const int* __restrict__ excl, const int* __restrict__ boff,
                                               int* __restrict__ row_ptr, int* __restrict__ cursor) {
    int gid = blockIdx.x * 256 + threadIdx.x;
    int v = excl[gid] + boff[gid >> 8];
    row_ptr[gid] = v;
    cursor[gid] = v;
    if (gid == 0) row_ptr[N_NODES] = N_EDGES;
}

// packed edge record (slot space): {src_slot, bf16(a0,a1), bf16(a2,a3), 0}
__global__ __launch_bounds__(256) void k_scatter(const int* __restrict__ ei, const float* __restrict__ ea,
                                                 const int* __restrict__ slot_of,
                                                 int* __restrict__ cursor, int4* __restrict__ csr_pk) {
    int e = blockIdx.x * 256 + threadIdx.x;
    int ds = slot_of[ei[N_EDGES + e]];
    int pos = atomicAdd(&cursor[ds], 1);
    float4 a = ((const float4*)ea)[e];
    unsigned a01 = bf16_rne(a.x) | (bf16_rne(a.y) << 16);
    unsigned a23 = bf16_rne(a.z) | (bf16_rne(a.w) << 16);
    csr_pk[pos] = make_int4(slot_of[ei[e]], (int)a01, (int)a23, 0);
}

// ---------------- prep: bf16 B-fragment weight tiles ----------------
#define WB_SZ (4 * 40 * 512)
__global__ __launch_bounds__(256) void k_prep(const float* __restrict__ wih, const float* __restrict__ whh,
                                              const float* __restrict__ rw, const float* __restrict__ w1,
                                              const float* __restrict__ bih, const float* __restrict__ bhh,
                                              const float* __restrict__ nn1w, const float* __restrict__ nn1b,
                                              __bf16* __restrict__ Wb, __bf16* __restrict__ B2b,
                                              __bf16* __restrict__ w1b) {
    int idx = blockIdx.x * 256 + threadIdx.x;
    if (idx < WB_SZ) {
        int j = idx / 20480, r = idx % 20480;
        int t = r >> 9, e = r & 511;
        int jj = e & 7, c16 = (e >> 3) & 15, kq = e >> 7;
        int ct, kk; bool nih = false;
        if (t < 36) { ct = t / 3; kk = t % 3; } else { ct = 8 + (t - 36); kk = 0; nih = true; }
        int k = kk * 32 + kq * 8 + jj;
        int c = ct * 16 + c16;
        bool ngate = ct >= 8;
        float v = 0.f;
        if (nih) {
            if (k < 16) v = wih[((size_t)j * 192 + c) * 16 + k];
        } else {
            if (k < 16) v = ngate ? 0.f : wih[((size_t)j * 192 + c) * 16 + k];
            else if (k < 80) v = whh[((size_t)j * 192 + c) * 64 + (k - 16)];
            else if (k == 80) v = ngate ? bhh[j * 192 + c] : (bih[j * 192 + c] + bhh[j * 192 + c]);
        }
        Wb[idx] = (__bf16)v;
    } else if (idx < WB_SZ + 1536) {
        int e = idx - WB_SZ;
        int t = e >> 9, ee = e & 511;
        int jj = ee & 7, c16 = (ee >> 3) & 15, kq = ee >> 7;
        int krow = t * 32 + kq * 8 + jj;
        float v;
        if (krow < 16) v = rw[krow * 16 + c16];
        else {
            int i = (krow - 16) >> 4, kk = (krow - 16) & 15;
            v = (i == 0) ? nn1b[kk * 16 + c16] : nn1w[(i - 1) * 256 + kk * 16 + c16];
        }
        B2b[e] = (__bf16)v;
    } else if (idx < WB_SZ + 1536 + 1024) {
        int e = idx - (WB_SZ + 1536);
        int t2 = e >> 9, ee = e & 511;
        int jj = ee & 7, c16 = (ee >> 3) & 15, kq = ee >> 7;
        int k = t2 * 32 + kq * 8 + jj;
        w1b[e] = (__bf16)w1[k * 16 + c16];
    }
}

// ---------------- init: h[slot] = relu(x[node] @ lin0_w + lin0_b) -> bf16 ----------------
__global__ __launch_bounds__(256) void k_init(const float* __restrict__ x, const float* __restrict__ w,
                                              const float* __restrict__ b, const int* __restrict__ slot_of,
                                              __bf16* __restrict__ h) {
    __shared__ float s_w[F_IN * DIM];
    int tid = threadIdx.x;
    for (int i = tid; i < F_IN * DIM; i += 256) s_w[i] = w[i];
    int node = blockIdx.x * 16 + (tid >> 4);
    int c4 = tid & 15;
    const float4* xp = (const float4*)(x + (size_t)node * F_IN);
    float4 x0 = xp[0], x1 = xp[1], x2 = xp[2], x3 = xp[3];
    float xa[16] = {x0.x, x0.y, x0.z, x0.w, x1.x, x1.y, x1.z, x1.w,
                    x2.x, x2.y, x2.z, x2.w, x3.x, x3.y, x3.z, x3.w};
    __syncthreads();
    float4 acc = ((const float4*)b)[c4];
    const float4* w4 = (const float4*)s_w;
#pragma unroll
    for (int k = 0; k < 16; ++k) {
        float4 wv = w4[k * 16 + c4];
        FMA4(acc, xa[k], wv);
    }
    bf16x4 hv;
    hv[0] = (__bf16)fmaxf(acc.x, 0.f); hv[1] = (__bf16)fmaxf(acc.y, 0.f);
    hv[2] = (__bf16)fmaxf(acc.z, 0.f); hv[3] = (__bf16)fmaxf(acc.w, 0.f);
    int s = slot_of[node];
    *(bf16x4*)&h[(size_t)s * DIM + c4 * 4] = hv;
}

// ---------------- out1 = h @ lin1_w + lin1_b (slot space; bf16 in/out) ----------------
__global__ __launch_bounds__(256) void k_lin1(const __bf16* __restrict__ h, const float* __restrict__ w,
                                              const float* __restrict__ b, __bf16* __restrict__ out1) {
    __shared__ float s_h[64 * 68];
    int tid = threadIdx.x;
    int nb = blockIdx.x * 64;
    for (int i = tid; i < 64 * 16; i += 256) {
        int n = i >> 4, q4 = i & 15;
        bf16x4 v = *(const bf16x4*)&h[(size_t)(nb + n) * 64 + q4 * 4];
        float* d = &s_h[n * 68 + q4 * 4];
        d[0] = (float)v[0]; d[1] = (float)v[1]; d[2] = (float)v[2]; d[3] = (float)v[3];
    }
    int ct = tid & 15;
    float wcol[64];
#pragma unroll
    for (int q = 0; q < 64; ++q) wcol[q] = w[q * 16 + ct];
    float bias = b[ct];
    __syncthreads();
    int ng = tid >> 4;
#pragma unroll
    for (int rep = 0; rep < 4; ++rep) {
        int nl = ng + 16 * rep;
        float acc = bias;
#pragma unroll
        for (int q4 = 0; q4 < 16; ++q4) {
            float4 hv = *(const float4*)&s_h[nl * 68 + q4 * 4];
            acc = fmaf(hv.x, wcol[4 * q4 + 0], acc);
            acc = fmaf(hv.y, wcol[4 * q4 + 1], acc);
            acc = fmaf(hv.z, wcol[4 * q4 + 2], acc);
            acc = fmaf(hv.w, wcol[4 * q4 + 3], acc);
        }
        out1[(size_t)(nb + nl) * 16 + ct] = (__bf16)acc;
    }
}

// ---------------- node v14: degree-sorted slots + packed gather + MFMA GRU ----------------
__attribute__((amdgpu_waves_per_eu(2, 4)))
__global__ __launch_bounds__(512) void k_node(
    const __bf16* __restrict__ out1_in, __bf16* __restrict__ out1_out,
    const int4* __restrict__ csr_pk,
    const int* __restrict__ row_ptr, const float* __restrict__ invs,
    __bf16* __restrict__ h, const __bf16* __restrict__ Wb, const __bf16* __restrict__ B2b,
    const __bf16* __restrict__ w1b, const float* __restrict__ conv_b,
    const float* __restrict__ bih, const float* __restrict__ lin1_b,
    const int* __restrict__ batchs, const float* __restrict__ lin2_w,
    float* __restrict__ out, int do_final)
{
    __shared__ __align__(16) __bf16 s_X[128 * 104];  // 26624 B
    __shared__ __align__(16) __bf16 s_W[40 * 512];   // 40960 B
    __shared__ __align__(16) __bf16 s_B2[3 * 512];   //  3072 B
    __shared__ __align__(16) __bf16 s_w1[1024];      //  2048 B  (total 72704)
    int tid = threadIdx.x;
    int nb = blockIdx.x * 128;
    int lane = tid & 63, w = tid >> 6;               // w = 0..7
    int c16 = lane & 15, lq = lane >> 4;
    int nwb = nb + w * 16;
    int xrow = w * 16;

    // cooperative staging of weight tiles (512 threads)
    {
        const float4* src = (const float4*)Wb;
        float4* dst = (float4*)s_W;
#pragma unroll
        for (int i = 0; i < 5; ++i) dst[tid + 512 * i] = src[tid + 512 * i];
        if (tid < 192) ((float4*)s_B2)[tid] = ((const float4*)B2b)[tid];
        else if (tid < 320) ((float4*)s_w1)[tid - 192] = ((const float4*)w1b)[tid - 192];
    }
    // own out1 row -> X2[.][0..15]  (wave-private rows)
    {
        int n = lane >> 2, k4 = lane & 3;
        bf16x4 v = *(const bf16x4*)&out1_in[(size_t)(nwb + n) * 16 + k4 * 4];
        *(bf16x4*)&s_X[(xrow + n) * 104 + k4 * 4] = v;
    }
    __syncthreads();   // the ONLY block-wide barrier (covers s_W/s_B2/s_w1)

    // gather: wave-private. group gi = lane>>4 handles slots nwb + gi*4 + r (r=0..3)
    {
        int gi = lane >> 4, k = lane & 15;
        int e0[4], dr[4];
        int4 pk[4];
        float S0[4] = {0.f,0.f,0.f,0.f}, S1[4] = {0.f,0.f,0.f,0.f}, S2[4] = {0.f,0.f,0.f,0.f},
              S3[4] = {0.f,0.f,0.f,0.f}, S4[4] = {0.f,0.f,0.f,0.f};
        int rounds = 0;
#pragma unroll
        for (int r = 0; r < 4; ++r) {
            int n = nwb + gi * 4 + r;
            e0[r] = row_ptr[n];
            dr[r] = row_ptr[n + 1] - e0[r];
            rounds = max(rounds, dr[r]);
            pk[r] = csr_pk[min(e0[r], N_EDGES - 1)];
        }
        for (int t = 0; t < rounds; ++t) {
            int4 pkn[4]; float xv[4];
#pragma unroll
            for (int r = 0; r < 4; ++r)
                pkn[r] = csr_pk[min(e0[r] + t + 1, N_EDGES - 1)];
#pragma unroll
            for (int r = 0; r < 4; ++r)
                xv[r] = (float)out1_in[(size_t)(pk[r].x & 0xFFFFF) * 16 + k];
#pragma unroll
            for (int r = 0; r < 4; ++r) {
                float xm = (t < dr[r]) ? xv[r] : 0.0f;
                float a0 = __uint_as_float(((unsigned)pk[r].y) << 16);
                float a1 = __uint_as_float(((unsigned)pk[r].y) & 0xffff0000u);
                float a2 = __uint_as_float(((unsigned)pk[r].z) << 16);
                float a3 = __uint_as_float(((unsigned)pk[r].z) & 0xffff0000u);
                S0[r] += xm;
                S1[r] = fmaf(a0, xm, S1[r]);
                S2[r] = fmaf(a1, xm, S2[r]);
                S3[r] = fmaf(a2, xm, S3[r]);
                S4[r] = fmaf(a3, xm, S4[r]);
                pk[r] = pkn[r];
            }
        }
#pragma unroll
        for (int r = 0; r < 4; ++r) {
            int nl = xrow + gi * 4 + r;
            float inv = invs[nwb + gi * 4 + r];
            __bf16* p = &s_X[nl * 104];
            p[16 + k] = (__bf16)(S0[r] * inv);
            p[32 + k] = (__bf16)(S1[r] * inv);
            p[48 + k] = (__bf16)(S2[r] * inv);
            p[64 + k] = (__bf16)(S3[r] * inv);
            p[80 + k] = (__bf16)(S4[r] * inv);
        }
    }
    // no barrier: s_X rows are wave-private; same-wave DS ops are in program order

    // phase 2: o2 = X2 @ B2 + conv_b (K=96)
    float cb = conv_b[c16];
    f32x4 co2 = (f32x4){cb, cb, cb, cb};
#pragma unroll
    for (int kk = 0; kk < 3; ++kk) {
        bf16x8 a = *(const bf16x8*)&s_X[(xrow + c16) * 104 + kk * 32 + lq * 8];
        bf16x8 b = *(const bf16x8*)&s_B2[kk * 512 + lane * 8];
        co2 = __builtin_amdgcn_mfma_f32_16x16x32_bf16(a, b, co2, 0, 0, 0);
    }

    // phase 3a: rebuild X = [o2(16) | h(64) | 1 | 0..]  (wave-own rows)
#pragma unroll
    for (int jr = 0; jr < 4; ++jr)
        s_X[(xrow + 4 * lq + jr) * 104 + c16] = (__bf16)co2[jr];
    {
        const bf16x8* hsrc = (const bf16x8*)(h + (size_t)nwb * 64);
#pragma unroll
        for (int ii = 0; ii < 2; ++ii) {
            int idx = lane + 64 * ii;
            int n = idx >> 3, d8 = idx & 7;
            bf16x8 v = hsrc[idx];
            *(bf16x8*)&s_X[(xrow + n) * 104 + 16 + d8 * 8] = v;
        }
    }
    {
        int n = lane >> 2, c0 = 80 + (lane & 3) * 4;
#pragma unroll
        for (int q = 0; q < 4; ++q)
            s_X[(xrow + n) * 104 + c0 + q] = (c0 + q == 80) ? (__bf16)1.0f : (__bf16)0.0f;
    }

    // phase 3b: gates GEMM
    f32x4 acc[12], ani4[4];
#pragma unroll
    for (int i = 0; i < 12; ++i) acc[i] = (f32x4){0.f, 0.f, 0.f, 0.f};
#pragma unroll
    for (int i = 0; i < 4; ++i) ani4[i] = (f32x4){0.f, 0.f, 0.f, 0.f};
    bf16x8 af[3];
#pragma unroll
    for (int kk = 0; kk < 3; ++kk)
        af[kk] = *(const bf16x8*)&s_X[(xrow + c16) * 104 + kk * 32 + lq * 8];
#pragma unroll
    for (int ct = 0; ct < 12; ++ct) {
#pragma unroll
        for (int kk = 0; kk < 3; ++kk) {
            bf16x8 bf = *(const bf16x8*)&s_W[(ct * 3 + kk) * 512 + lane * 8];
            acc[ct] = __builtin_amdgcn_mfma_f32_16x16x32_bf16(af[kk], bf, acc[ct], 0, 0, 0);
        }
    }
#pragma unroll
    for (int ct8 = 0; ct8 < 4; ++ct8) {
        bf16x8 bf = *(const bf16x8*)&s_W[(36 + ct8) * 512 + lane * 8];
        ani4[ct8] = __builtin_amdgcn_mfma_f32_16x16x32_bf16(af[0], bf, ani4[ct8], 0, 0, 0);
    }

    // GRU epilogue (hold from s_X bf16); keep h_new in registers
    float hn[4][4];
#pragma unroll
    for (int ct = 0; ct < 4; ++ct) {
        float bni = bih[128 + ct * 16 + c16];
#pragma unroll
        for (int jr = 0; jr < 4; ++jr) {
            float hold = (float)s_X[(xrow + 4 * lq + jr) * 104 + 16 + ct * 16 + c16];
            float rr = 1.f / (1.f + __expf(-acc[ct][jr]));
            float zz = 1.f / (1.f + __expf(-acc[4 + ct][jr]));
            float xx = fmaf(rr, acc[8 + ct][jr], ani4[ct][jr] + bni);
            float ax = fabsf(xx);
            float ee = __expf(-2.f * ax);
            float ncv = __builtin_copysignf((1.f - ee) / (1.f + ee), xx);
            hn[ct][jr] = fmaf(zz, hold - ncv, ncv);
        }
    }
    // write h_new into s_X (same-wave DS order), then coalesced bf16 writeback to h
#pragma unroll
    for (int ct = 0; ct < 4; ++ct)
#pragma unroll
        for (int jr = 0; jr < 4; ++jr)
            s_X[(xrow + 4 * lq + jr) * 104 + 16 + ct * 16 + c16] = (__bf16)hn[ct][jr];
    {
        bf16x8* hdst = (bf16x8*)(h + (size_t)nwb * 64);
#pragma unroll
        for (int ii = 0; ii < 2; ++ii) {
            int idx = lane + 64 * ii;
            int n = idx >> 3, d8 = idx & 7;
            bf16x8 v = *(const bf16x8*)&s_X[(xrow + n) * 104 + 16 + d8 * 8];
            hdst[idx] = v;
        }
    }

    if (!do_final) {
        // fused lin1 -> out1_out (bf16)
        f32x4 o1acc = (f32x4){0.f, 0.f, 0.f, 0.f};
#pragma unroll
        for (int kk = 0; kk < 2; ++kk) {
            bf16x8 a = *(const bf16x8*)&s_X[(xrow + c16) * 104 + 16 + kk * 32 + lq * 8];
            bf16x8 b = *(const bf16x8*)&s_w1[kk * 512 + lane * 8];
            o1acc = __builtin_amdgcn_mfma_f32_16x16x32_bf16(a, b, o1acc, 0, 0, 0);
        }
        float lb = lin1_b[c16];
#pragma unroll
        for (int jr = 0; jr < 4; ++jr) {
            int node = nwb + 4 * lq + jr;
            out1_out[(size_t)node * 16 + c16] = (__bf16)(o1acc[jr] + lb);
        }
    } else {
        // fused final: y = h_new @ lin2_w ; atomicAdd into out[batchs]
        float w2v[4];
#pragma unroll
        for (int ct = 0; ct < 4; ++ct) w2v[ct] = lin2_w[ct * 16 + c16];
#pragma unroll
        for (int jr = 0; jr < 4; ++jr) {
            float part = hn[0][jr] * w2v[0];
            part = fmaf(hn[1][jr], w2v[1], part);
            part = fmaf(hn[2][jr], w2v[2], part);
            part = fmaf(hn[3][jr], w2v[3], part);
#pragma unroll
            for (int off = 8; off > 0; off >>= 1) part += __shfl_xor(part, off, 64);
            if (c16 == 0) {
                int node = nwb + 4 * lq + jr;
                atomicAdd(&out[batchs[node]], part);
            }
        }
    }
}

extern "C" void kernel_launch(void* const* d_in, const int* in_sizes, int n_in,
                              void* d_out, int out_size, void* d_ws, size_t ws_size,
                              hipStream_t stream) {
    const float* x        = (const float*)d_in[0];
    const float* edge_attr= (const float*)d_in[1];
    const float* lin0_w   = (const float*)d_in[2];
    const float* lin0_b   = (const float*)d_in[3];
    const float* nn1_w    = (const float*)d_in[4];
    const float* nn1_b    = (const float*)d_in[5];
    const float* root_w   = (const float*)d_in[6];
    const float* conv_b   = (const float*)d_in[7];
    const float* gru_w_ih = (const float*)d_in[8];
    const float* gru_w_hh = (const float*)d_in[9];
    const float* gru_b_ih = (const float*)d_in[10];
    const float* gru_b_hh = (const float*)d_in[11];
    const float* lin1_w   = (const float*)d_in[12];
    const float* lin1_b   = (const float*)d_in[13];
    const float* lin2_w   = (const float*)d_in[14];
    const int*   ei       = (const int*)d_in[15];
    const int*   batch    = (const int*)d_in[16];
    float* out = (float*)d_out;

    char* p = (char*)d_ws;
    __bf16* h       = (__bf16*)p;           p += (size_t)N_NODES * DIM * 2;
    __bf16* out1A   = (__bf16*)p;           p += (size_t)N_NODES * DNN * 2;
    __bf16* out1B   = (__bf16*)p;           p += (size_t)N_NODES * DNN * 2;
    int4*   csr_pk  = (int4*)p;             p += (size_t)N_EDGES * 16;
    __bf16* Wb      = (__bf16*)p;           p += (size_t)WB_SZ * 2;
    __bf16* B2b     = (__bf16*)p;           p += 1536 * 2;
    __bf16* w1b     = (__bf16*)p;           p += 1024 * 2;
    int*    cnt     = (int*)p;              p += (size_t)N_NODES * 4;
    float*  invs    = (float*)p;            p += (size_t)N_NODES * 4;
    int*    row_ptr = (int*)p;              p += (size_t)(N_NODES + 16) * 4;
    int*    cursor  = (int*)p;              p += (size_t)N_NODES * 4;
    int*    excl    = (int*)p;              p += (size_t)N_NODES * 4;
    int*    bsum    = (int*)p;              p += 512 * 4;
    int*    boff    = (int*)p;              p += 512 * 4;
    int*    slot_of = (int*)p;              p += (size_t)N_NODES * 4;
    int*    cnts    = (int*)p;              p += (size_t)N_NODES * 4;
    int*    batchs  = (int*)p;              p += (size_t)N_NODES * 4;
    int*    hist    = (int*)p;              p += 32 * 4;
    int*    binoff  = (int*)p;              p += 32 * 4;
    int*    bincur  = (int*)p;              p += 32 * 4;

    hipMemsetAsync(d_out, 0, (size_t)NG * 4, stream);
    hipMemsetAsync(cnt, 0, (size_t)N_NODES * 4, stream);
    hipMemsetAsync(hist, 0, 32 * 4, stream);
    hipMemsetAsync(bincur, 0, 32 * 4, stream);
    k_prep<<<330, 256, 0, stream>>>(gru_w_ih, gru_w_hh, root_w, lin1_w, gru_b_ih, gru_b_hh,
                                    nn1_w, nn1_b, Wb, B2b, w1b);
    k_degree<<<N_EDGES / 256, 256, 0, stream>>>(ei, cnt);
    k_hist<<<N_NODES / 256, 256, 0, stream>>>(cnt, hist);
    k_binoff<<<1, 64, 0, stream>>>(hist, binoff);
    k_permute<<<N_NODES / 256, 256, 0, stream>>>(cnt, binoff, bincur, batch,
                                                 slot_of, cnts, invs, batchs);
    k_scanA<<<N_NODES / 256, 256, 0, stream>>>(cnts, excl, bsum);
    k_scanB<<<1, 256, 0, stream>>>(bsum, boff);
    k_scanC<<<N_NODES / 256, 256, 0, stream>>>(excl, boff, row_ptr, cursor);
    k_scatter<<<N_EDGES / 256, 256, 0, stream>>>(ei, edge_attr, slot_of, cursor, csr_pk);
    k_init<<<N_NODES / 16, 256, 0, stream>>>(x, lin0_w, lin0_b, slot_of, h);
    k_lin1<<<N_NODES / 64, 256, 0, stream>>>(h, lin1_w, lin1_b, out1A);

    for (int it = 0; it < N_ITERS; ++it) {
        int j = it >> 1;   // GRU index (NL2 = 2)
        const __bf16* o_in = (it & 1) ? out1B : out1A;
        __bf16*       o_out= (it & 1) ? out1A : out1B;
        k_node<<<N_NODES / 128, 512, 0, stream>>>(o_in, o_out, csr_pk, row_ptr, invs,
                                                  h, Wb + (size_t)j * 40 * 512, B2b, w1b,
                                                  conv_b, gru_b_ih + (size_t)j * 192, lin1_b,
                                                  batchs, lin2_w, out, it == N_ITERS - 1 ? 1 : 0);
    }
}

// Round 22
// 329.893 us; speedup vs baseline: 4.3086x; 1.1143x over previous
//
#include <hip/hip_runtime.h>
#include <hip/hip_bf16.h>

#define N_NODES 131072
#define N_EDGES 524288
#define F_IN 16
#define DIM 64
#define DNN 16
#define BK 4
#define NG 8192
#define N_ITERS 8   // NL1*NL2

typedef __bf16 bf16x8 __attribute__((ext_vector_type(8)));
typedef __bf16 bf16x4 __attribute__((ext_vector_type(4)));
typedef float f32x4 __attribute__((ext_vector_type(4)));

#define FMA4(A_, S_, W_) { (A_).x = fmaf((S_), (W_).x, (A_).x); (A_).y = fmaf((S_), (W_).y, (A_).y); \
                           (A_).z = fmaf((S_), (W_).z, (A_).z); (A_).w = fmaf((S_), (W_).w, (A_).w); }

__device__ __forceinline__ unsigned bf16_rne(float f) {
    unsigned u = __float_as_uint(f);
    return (u + 0x7fffu + ((u >> 16) & 1u)) >> 16;
}

// ---------------- degree (int, node-indexed) ----------------
__global__ __launch_bounds__(256) void k_degree(const int* __restrict__ ei, int* __restrict__ cnt) {
    int e = blockIdx.x * 256 + threadIdx.x;
    atomicAdd(&cnt[ei[N_EDGES + e]], 1);
}

// ---------------- degree-descending counting sort (two-level histogram) ----------------
__global__ __launch_bounds__(256) void k_hist(const int* __restrict__ cnt, int* __restrict__ hist) {
    __shared__ int lh[32];
    int tid = threadIdx.x;
    if (tid < 32) lh[tid] = 0;
    __syncthreads();
    int n = blockIdx.x * 256 + tid;
    int key = 31 - min(cnt[n], 31);            // slot ascending == degree descending
    atomicAdd(&lh[key], 1);
    __syncthreads();
    if (tid < 32 && lh[tid]) atomicAdd(&hist[tid], lh[tid]);
}

__global__ __launch_bounds__(64) void k_binoff(const int* __restrict__ hist, int* __restrict__ binoff) {
    if (threadIdx.x == 0) {
        int acc = 0;
#pragma unroll
        for (int i = 0; i < 32; ++i) { binoff[i] = acc; acc += hist[i]; }
    }
}

// slot_of[node]; per-slot arrays: cnts, invs, batchs
__global__ __launch_bounds__(256) void k_permute(const int* __restrict__ cnt, const int* __restrict__ binoff,
                                                 int* __restrict__ bincur, const int* __restrict__ batch,
                                                 int* __restrict__ slot_of, int* __restrict__ cnts,
                                                 float* __restrict__ invs, int* __restrict__ batchs) {
    __shared__ int lh[32], lbase[32];
    int tid = threadIdx.x;
    if (tid < 32) lh[tid] = 0;
    __syncthreads();
    int n = blockIdx.x * 256 + tid;
    int deg = cnt[n];
    int key = 31 - min(deg, 31);
    int myrank = atomicAdd(&lh[key], 1);       // LDS atomic: block-local rank
    __syncthreads();
    if (tid < 32) lbase[tid] = lh[tid] ? atomicAdd(&bincur[tid], lh[tid]) : 0;
    __syncthreads();
    int slot = binoff[key] + lbase[key] + myrank;
    slot_of[n] = slot;
    cnts[slot] = deg;
    invs[slot] = 1.0f / (float)max(deg, 1);
    batchs[slot] = batch[n];
}

// ---------------- CSR scan (slot-indexed) ----------------
__global__ __launch_bounds__(256) void k_scanA(const int* __restrict__ cnt, int* __restrict__ excl,
                                               int* __restrict__ bsum) {
    __shared__ int a[256], b[256];
    int t = threadIdx.x, gid = blockIdx.x * 256 + t;
    int c = cnt[gid];
    a[t] = c; __syncthreads();
    int *s = a, *d = b;
#pragma unroll
    for (int off = 1; off < 256; off <<= 1) {
        d[t] = s[t] + (t >= off ? s[t - off] : 0);
        __syncthreads();
        int* tmp = s; s = d; d = tmp;
    }
    excl[gid] = s[t] - c;
    if (t == 255) bsum[blockIdx.x] = s[255];
}

__global__ __launch_bounds__(256) void k_scanB(const int* __restrict__ bsum, int* __restrict__ boff) {
    __shared__ int a[512], b[512];
    int t = threadIdx.x;
    a[t] = bsum[t]; a[t + 256] = bsum[t + 256];
    __syncthreads();
    int *s = a, *d = b;
#pragma unroll
    for (int off = 1; off < 512; off <<= 1) {
        d[t] = s[t] + (t >= off ? s[t - off] : 0);
        int i2 = t + 256;
        d[i2] = s[i2] + (i2 >= off ? s[i2 - off] : 0);
        __syncthreads();
        int* tmp = s; s = d; d = tmp;
    }
    boff[t] = t ? s[t - 1] : 0;
    boff[t + 256] = s[t + 255];
}

__global__ __launch_bounds__(256) void k_scanC(const int* __restrict__ excl, const int* __restrict__ boff,
                                               int* __restrict__ row_ptr, int* __restrict__ cursor) {
    int gid = blockIdx.x * 256 + threadIdx.x;
    int v = excl[gid] + boff[gid >> 8];
    row_ptr[gid] = v;
    cursor[gid] = v;
    if (gid == 0) row_ptr[N_NODES] = N_EDGES;
}

// packed edge record (slot space): {src_slot, bf16(a0,a1), bf16(a2,a3), 0}
__global__ __launch_bounds__(256) void k_scatter(const int* __restrict__ ei, const float* __restrict__ ea,
                                                 const int* __restrict__ slot_of,
                                                 int* __restrict__ cursor, int4* __restrict__ csr_pk) {
    int e = blockIdx.x * 256 + threadIdx.x;
    int ds = slot_of[ei[N_EDGES + e]];
    int pos = atomicAdd(&cursor[ds], 1);
    float4 a = ((const float4*)ea)[e];
    unsigned a01 = bf16_rne(a.x) | (bf16_rne(a.y) << 16);
    unsigned a23 = bf16_rne(a.z) | (bf16_rne(a.w) << 16);
    csr_pk[pos] = make_int4(slot_of[ei[e]], (int)a01, (int)a23, 0);
}

// ---------------- prep: bf16 B-fragment weight tiles + zero cnt/hist/bincur ----------------
#define WB_SZ (4 * 40 * 512)
__global__ __launch_bounds__(256) void k_prep(const float* __restrict__ wih, const float* __restrict__ whh,
                                              const float* __restrict__ rw, const float* __restrict__ w1,
                                              const float* __restrict__ bih, const float* __restrict__ bhh,
                                              const float* __restrict__ nn1w, const float* __restrict__ nn1b,
                                              __bf16* __restrict__ Wb, __bf16* __restrict__ B2b,
                                              __bf16* __restrict__ w1b, int* __restrict__ cnt,
                                              int* __restrict__ hist, int* __restrict__ bincur) {
    int idx = blockIdx.x * 256 + threadIdx.x;
    if (idx < N_NODES) cnt[idx] = 0;           // grid = 512 blocks covers all
    if (idx < 32) { hist[idx] = 0; bincur[idx] = 0; }
    if (idx < WB_SZ) {
        int j = idx / 20480, r = idx % 20480;
        int t = r >> 9, e = r & 511;
        int jj = e & 7, c16 = (e >> 3) & 15, kq = e >> 7;
        int ct, kk; bool nih = false;
        if (t < 36) { ct = t / 3; kk = t % 3; } else { ct = 8 + (t - 36); kk = 0; nih = true; }
        int k = kk * 32 + kq * 8 + jj;
        int c = ct * 16 + c16;
        bool ngate = ct >= 8;
        float v = 0.f;
        if (nih) {
            if (k < 16) v = wih[((size_t)j * 192 + c) * 16 + k];
        } else {
            if (k < 16) v = ngate ? 0.f : wih[((size_t)j * 192 + c) * 16 + k];
            else if (k < 80) v = whh[((size_t)j * 192 + c) * 64 + (k - 16)];
            else if (k == 80) v = ngate ? bhh[j * 192 + c] : (bih[j * 192 + c] + bhh[j * 192 + c]);
        }
        Wb[idx] = (__bf16)v;
    } else if (idx < WB_SZ + 1536) {
        int e = idx - WB_SZ;
        int t = e >> 9, ee = e & 511;
        int jj = ee & 7, c16 = (ee >> 3) & 15, kq = ee >> 7;
        int krow = t * 32 + kq * 8 + jj;
        float v;
        if (krow < 16) v = rw[krow * 16 + c16];
        else {
            int i = (krow - 16) >> 4, kk = (krow - 16) & 15;
            v = (i == 0) ? nn1b[kk * 16 + c16] : nn1w[(i - 1) * 256 + kk * 16 + c16];
        }
        B2b[e] = (__bf16)v;
    } else if (idx < WB_SZ + 1536 + 1024) {
        int e = idx - (WB_SZ + 1536);
        int t2 = e >> 9, ee = e & 511;
        int jj = ee & 7, c16 = (ee >> 3) & 15, kq = ee >> 7;
        int k = t2 * 32 + kq * 8 + jj;
        w1b[e] = (__bf16)w1[k * 16 + c16];
    }
}

// ---------------- init: h[slot] = relu(x[node] @ lin0_w + lin0_b) -> bf16 ----------------
__global__ __launch_bounds__(256) void k_init(const float* __restrict__ x, const float* __restrict__ w,
                                              const float* __restrict__ b, const int* __restrict__ slot_of,
                                              __bf16* __restrict__ h) {
    __shared__ float s_w[F_IN * DIM];
    int tid = threadIdx.x;
    for (int i = tid; i < F_IN * DIM; i += 256) s_w[i] = w[i];
    int node = blockIdx.x * 16 + (tid >> 4);
    int c4 = tid & 15;
    const float4* xp = (const float4*)(x + (size_t)node * F_IN);
    float4 x0 = xp[0], x1 = xp[1], x2 = xp[2], x3 = xp[3];
    float xa[16] = {x0.x, x0.y, x0.z, x0.w, x1.x, x1.y, x1.z, x1.w,
                    x2.x, x2.y, x2.z, x2.w, x3.x, x3.y, x3.z, x3.w};
    __syncthreads();
    float4 acc = ((const float4*)b)[c4];
    const float4* w4 = (const float4*)s_w;
#pragma unroll
    for (int k = 0; k < 16; ++k) {
        float4 wv = w4[k * 16 + c4];
        FMA4(acc, xa[k], wv);
    }
    bf16x4 hv;
    hv[0] = (__bf16)fmaxf(acc.x, 0.f); hv[1] = (__bf16)fmaxf(acc.y, 0.f);
    hv[2] = (__bf16)fmaxf(acc.z, 0.f); hv[3] = (__bf16)fmaxf(acc.w, 0.f);
    int s = slot_of[node];
    *(bf16x4*)&h[(size_t)s * DIM + c4 * 4] = hv;
}

// ---------------- out1 = h @ lin1_w + lin1_b (slot space; bf16 in/out) ----------------
__global__ __launch_bounds__(256) void k_lin1(const __bf16* __restrict__ h, const float* __restrict__ w,
                                              const float* __restrict__ b, __bf16* __restrict__ out1) {
    __shared__ float s_h[64 * 68];
    int tid = threadIdx.x;
    int nb = blockIdx.x * 64;
    for (int i = tid; i < 64 * 16; i += 256) {
        int n = i >> 4, q4 = i & 15;
        bf16x4 v = *(const bf16x4*)&h[(size_t)(nb + n) * 64 + q4 * 4];
        float* d = &s_h[n * 68 + q4 * 4];
        d[0] = (float)v[0]; d[1] = (float)v[1]; d[2] = (float)v[2]; d[3] = (float)v[3];
    }
    int ct = tid & 15;
    float wcol[64];
#pragma unroll
    for (int q = 0; q < 64; ++q) wcol[q] = w[q * 16 + ct];
    float bias = b[ct];
    __syncthreads();
    int ng = tid >> 4;
#pragma unroll
    for (int rep = 0; rep < 4; ++rep) {
        int nl = ng + 16 * rep;
        float acc = bias;
#pragma unroll
        for (int q4 = 0; q4 < 16; ++q4) {
            float4 hv = *(const float4*)&s_h[nl * 68 + q4 * 4];
            acc = fmaf(hv.x, wcol[4 * q4 + 0], acc);
            acc = fmaf(hv.y, wcol[4 * q4 + 1], acc);
            acc = fmaf(hv.z, wcol[4 * q4 + 2], acc);
            acc = fmaf(hv.w, wcol[4 * q4 + 3], acc);
        }
        out1[(size_t)(nb + nl) * 16 + ct] = (__bf16)acc;
    }
}

// ---------------- node v15: 3-deep pipelined gather + rcp epilogue + MFMA GRU ----------------
// vs v14: (1) pk prefetched 2 rounds ahead so xv(t+1) issues during round t's
// accumulate -> steady-state round cost ~= VALU work, not L2 latency;
// (2) sigmoid/tanh divisions -> __builtin_amdgcn_rcpf (1 trans op vs ~10 VALU).
__attribute__((amdgpu_waves_per_eu(2, 4)))
__global__ __launch_bounds__(512) void k_node(
    const __bf16* __restrict__ out1_in, __bf16* __restrict__ out1_out,
    const int4* __restrict__ csr_pk,
    const int* __restrict__ row_ptr, const float* __restrict__ invs,
    __bf16* __restrict__ h, const __bf16* __restrict__ Wb, const __bf16* __restrict__ B2b,
    const __bf16* __restrict__ w1b, const float* __restrict__ conv_b,
    const float* __restrict__ bih, const float* __restrict__ lin1_b,
    const int* __restrict__ batchs, const float* __restrict__ lin2_w,
    float* __restrict__ out, int do_final)
{
    __shared__ __align__(16) __bf16 s_X[128 * 104];  // 26624 B
    __shared__ __align__(16) __bf16 s_W[40 * 512];   // 40960 B
    __shared__ __align__(16) __bf16 s_B2[3 * 512];   //  3072 B
    __shared__ __align__(16) __bf16 s_w1[1024];      //  2048 B  (total 72704)
    int tid = threadIdx.x;
    int nb = blockIdx.x * 128;
    int lane = tid & 63, w = tid >> 6;               // w = 0..7
    int c16 = lane & 15, lq = lane >> 4;
    int nwb = nb + w * 16;
    int xrow = w * 16;

    // cooperative staging of weight tiles (512 threads)
    {
        const float4* src = (const float4*)Wb;
        float4* dst = (float4*)s_W;
#pragma unroll
        for (int i = 0; i < 5; ++i) dst[tid + 512 * i] = src[tid + 512 * i];
        if (tid < 192) ((float4*)s_B2)[tid] = ((const float4*)B2b)[tid];
        else if (tid < 320) ((float4*)s_w1)[tid - 192] = ((const float4*)w1b)[tid - 192];
    }
    // own out1 row -> X2[.][0..15]  (wave-private rows)
    {
        int n = lane >> 2, k4 = lane & 3;
        bf16x4 v = *(const bf16x4*)&out1_in[(size_t)(nwb + n) * 16 + k4 * 4];
        *(bf16x4*)&s_X[(xrow + n) * 104 + k4 * 4] = v;
    }
    __syncthreads();   // the ONLY block-wide barrier (covers s_W/s_B2/s_w1)

    // gather: wave-private, 3-deep pipelined. group gi = lane>>4, slots nwb+gi*4+r
    {
        int gi = lane >> 4, k = lane & 15;
        int e0[4], dr[4];
        int4 pk0[4], pk1[4];
        float xv0[4];
        float S0[4] = {0.f,0.f,0.f,0.f}, S1[4] = {0.f,0.f,0.f,0.f}, S2[4] = {0.f,0.f,0.f,0.f},
              S3[4] = {0.f,0.f,0.f,0.f}, S4[4] = {0.f,0.f,0.f,0.f};
        int rounds = 0;
#pragma unroll
        for (int r = 0; r < 4; ++r) {
            int n = nwb + gi * 4 + r;
            e0[r] = row_ptr[n];
            dr[r] = row_ptr[n + 1] - e0[r];
            rounds = max(rounds, dr[r]);
            pk0[r] = csr_pk[min(e0[r], N_EDGES - 1)];
        }
#pragma unroll
        for (int r = 0; r < 4; ++r) pk1[r] = csr_pk[min(e0[r] + 1, N_EDGES - 1)];
#pragma unroll
        for (int r = 0; r < 4; ++r) xv0[r] = (float)out1_in[(size_t)(pk0[r].x & 0xFFFFF) * 16 + k];
        for (int t = 0; t < rounds; ++t) {
            int4 pk2[4]; float xv1[4];
#pragma unroll
            for (int r = 0; r < 4; ++r)
                pk2[r] = csr_pk[min(e0[r] + t + 2, N_EDGES - 1)];
#pragma unroll
            for (int r = 0; r < 4; ++r)
                xv1[r] = (float)out1_in[(size_t)(pk1[r].x & 0xFFFFF) * 16 + k];
#pragma unroll
            for (int r = 0; r < 4; ++r) {
                float xm = (t < dr[r]) ? xv0[r] : 0.0f;
                float a0 = __uint_as_float(((unsigned)pk0[r].y) << 16);
                float a1 = __uint_as_float(((unsigned)pk0[r].y) & 0xffff0000u);
                float a2 = __uint_as_float(((unsigned)pk0[r].z) << 16);
                float a3 = __uint_as_float(((unsigned)pk0[r].z) & 0xffff0000u);
                S0[r] += xm;
                S1[r] = fmaf(a0, xm, S1[r]);
                S2[r] = fmaf(a1, xm, S2[r]);
                S3[r] = fmaf(a2, xm, S3[r]);
                S4[r] = fmaf(a3, xm, S4[r]);
                pk0[r] = pk1[r]; pk1[r] = pk2[r]; xv0[r] = xv1[r];
            }
        }
#pragma unroll
        for (int r = 0; r < 4; ++r) {
            int nl = xrow + gi * 4 + r;
            float inv = invs[nwb + gi * 4 + r];
            __bf16* p = &s_X[nl * 104];
            p[16 + k] = (__bf16)(S0[r] * inv);
            p[32 + k] = (__bf16)(S1[r] * inv);
            p[48 + k] = (__bf16)(S2[r] * inv);
            p[64 + k] = (__bf16)(S3[r] * inv);
            p[80 + k] = (__bf16)(S4[r] * inv);
        }
    }
    // no barrier: s_X rows are wave-private; same-wave DS ops are in program order

    // phase 2: o2 = X2 @ B2 + conv_b (K=96)
    float cb = conv_b[c16];
    f32x4 co2 = (f32x4){cb, cb, cb, cb};
#pragma unroll
    for (int kk = 0; kk < 3; ++kk) {
        bf16x8 a = *(const bf16x8*)&s_X[(xrow + c16) * 104 + kk * 32 + lq * 8];
        bf16x8 b = *(const bf16x8*)&s_B2[kk * 512 + lane * 8];
        co2 = __builtin_amdgcn_mfma_f32_16x16x32_bf16(a, b, co2, 0, 0, 0);
    }

    // phase 3a: rebuild X = [o2(16) | h(64) | 1 | 0..]  (wave-own rows)
#pragma unroll
    for (int jr = 0; jr < 4; ++jr)
        s_X[(xrow + 4 * lq + jr) * 104 + c16] = (__bf16)co2[jr];
    {
        const bf16x8* hsrc = (const bf16x8*)(h + (size_t)nwb * 64);
#pragma unroll
        for (int ii = 0; ii < 2; ++ii) {
            int idx = lane + 64 * ii;
            int n = idx >> 3, d8 = idx & 7;
            bf16x8 v = hsrc[idx];
            *(bf16x8*)&s_X[(xrow + n) * 104 + 16 + d8 * 8] = v;
        }
    }
    {
        int n = lane >> 2, c0 = 80 + (lane & 3) * 4;
#pragma unroll
        for (int q = 0; q < 4; ++q)
            s_X[(xrow + n) * 104 + c0 + q] = (c0 + q == 80) ? (__bf16)1.0f : (__bf16)0.0f;
    }

    // phase 3b: gates GEMM
    f32x4 acc[12], ani4[4];
#pragma unroll
    for (int i = 0; i < 12; ++i) acc[i] = (f32x4){0.f, 0.f, 0.f, 0.f};
#pragma unroll
    for (int i = 0; i < 4; ++i) ani4[i] = (f32x4){0.f, 0.f, 0.f, 0.f};
    bf16x8 af[3];
#pragma unroll
    for (int kk = 0; kk < 3; ++kk)
        af[kk] = *(const bf16x8*)&s_X[(xrow + c16) * 104 + kk * 32 + lq * 8];
#pragma unroll
    for (int ct = 0; ct < 12; ++ct) {
#pragma unroll
        for (int kk = 0; kk < 3; ++kk) {
            bf16x8 bf = *(const bf16x8*)&s_W[(ct * 3 + kk) * 512 + lane * 8];
            acc[ct] = __builtin_amdgcn_mfma_f32_16x16x32_bf16(af[kk], bf, acc[ct], 0, 0, 0);
        }
    }
#pragma unroll
    for (int ct8 = 0; ct8 < 4; ++ct8) {
        bf16x8 bf = *(const bf16x8*)&s_W[(36 + ct8) * 512 + lane * 8];
        ani4[ct8] = __builtin_amdgcn_mfma_f32_16x16x32_bf16(af[0], bf, ani4[ct8], 0, 0, 0);
    }

    // GRU epilogue (hold from s_X bf16); fast rcp for sigmoid/tanh
    float hn[4][4];
#pragma unroll
    for (int ct = 0; ct < 4; ++ct) {
        float bni = bih[128 + ct * 16 + c16];
#pragma unroll
        for (int jr = 0; jr < 4; ++jr) {
            float hold = (float)s_X[(xrow + 4 * lq + jr) * 104 + 16 + ct * 16 + c16];
            float rr = __builtin_amdgcn_rcpf(1.f + __expf(-acc[ct][jr]));
            float zz = __builtin_amdgcn_rcpf(1.f + __expf(-acc[4 + ct][jr]));
            float xx = fmaf(rr, acc[8 + ct][jr], ani4[ct][jr] + bni);
            float ax = fabsf(xx);
            float ee = __expf(-2.f * ax);
            float ncv = __builtin_copysignf((1.f - ee) * __builtin_amdgcn_rcpf(1.f + ee), xx);
            hn[ct][jr] = fmaf(zz, hold - ncv, ncv);
        }
    }
    // write h_new into s_X (same-wave DS order), then coalesced bf16 writeback to h
#pragma unroll
    for (int ct = 0; ct < 4; ++ct)
#pragma unroll
        for (int jr = 0; jr < 4; ++jr)
            s_X[(xrow + 4 * lq + jr) * 104 + 16 + ct * 16 + c16] = (__bf16)hn[ct][jr];
    {
        bf16x8* hdst = (bf16x8*)(h + (size_t)nwb * 64);
#pragma unroll
        for (int ii = 0; ii < 2; ++ii) {
            int idx = lane + 64 * ii;
            int n = idx >> 3, d8 = idx & 7;
            bf16x8 v = *(const bf16x8*)&s_X[(xrow + n) * 104 + 16 + d8 * 8];
            hdst[idx] = v;
        }
    }

    if (!do_final) {
        // fused lin1 -> out1_out (bf16)
        f32x4 o1acc = (f32x4){0.f, 0.f, 0.f, 0.f};
#pragma unroll
        for (int kk = 0; kk < 2; ++kk) {
            bf16x8 a = *(const bf16x8*)&s_X[(xrow + c16) * 104 + 16 + kk * 32 + lq * 8];
            bf16x8 b = *(const bf16x8*)&s_w1[kk * 512 + lane * 8];
            o1acc = __builtin_amdgcn_mfma_f32_16x16x32_bf16(a, b, o1acc, 0, 0, 0);
        }
        float lb = lin1_b[c16];
#pragma unroll
        for (int jr = 0; jr < 4; ++jr) {
            int node = nwb + 4 * lq + jr;
            out1_out[(size_t)node * 16 + c16] = (__bf16)(o1acc[jr] + lb);
        }
    } else {
        // fused final: y = h_new @ lin2_w ; atomicAdd into out[batchs]
        float w2v[4];
#pragma unroll
        for (int ct = 0; ct < 4; ++ct) w2v[ct] = lin2_w[ct * 16 + c16];
#pragma unroll
        for (int jr = 0; jr < 4; ++jr) {
            float part = hn[0][jr] * w2v[0];
            part = fmaf(hn[1][jr], w2v[1], part);
            part = fmaf(hn[2][jr], w2v[2], part);
            part = fmaf(hn[3][jr], w2v[3], part);
#pragma unroll
            for (int off = 8; off > 0; off >>= 1) part += __shfl_xor(part, off, 64);
            if (c16 == 0) {
                int node = nwb + 4 * lq + jr;
                atomicAdd(&out[batchs[node]], part);
            }
        }
    }
}

extern "C" void kernel_launch(void* const* d_in, const int* in_sizes, int n_in,
                              void* d_out, int out_size, void* d_ws, size_t ws_size,
                              hipStream_t stream) {
    const float* x        = (const float*)d_in[0];
    const float* edge_attr= (const float*)d_in[1];
    const float* lin0_w   = (const float*)d_in[2];
    const float* lin0_b   = (const float*)d_in[3];
    const float* nn1_w    = (const float*)d_in[4];
    const float* nn1_b    = (const float*)d_in[5];
    const float* root_w   = (const float*)d_in[6];
    const float* conv_b   = (const float*)d_in[7];
    const float* gru_w_ih = (const float*)d_in[8];
    const float* gru_w_hh = (const float*)d_in[9];
    const float* gru_b_ih = (const float*)d_in[10];
    const float* gru_b_hh = (const float*)d_in[11];
    const float* lin1_w   = (const float*)d_in[12];
    const float* lin1_b   = (const float*)d_in[13];
    const float* lin2_w   = (const float*)d_in[14];
    const int*   ei       = (const int*)d_in[15];
    const int*   batch    = (const int*)d_in[16];
    float* out = (float*)d_out;

    char* p = (char*)d_ws;
    __bf16* h       = (__bf16*)p;           p += (size_t)N_NODES * DIM * 2;
    __bf16* out1A   = (__bf16*)p;           p += (size_t)N_NODES * DNN * 2;
    __bf16* out1B   = (__bf16*)p;           p += (size_t)N_NODES * DNN * 2;
    int4*   csr_pk  = (int4*)p;             p += (size_t)N_EDGES * 16;
    __bf16* Wb      = (__bf16*)p;           p += (size_t)WB_SZ * 2;
    __bf16* B2b     = (__bf16*)p;           p += 1536 * 2;
    __bf16* w1b     = (__bf16*)p;           p += 1024 * 2;
    int*    cnt     = (int*)p;              p += (size_t)N_NODES * 4;
    float*  invs    = (float*)p;            p += (size_t)N_NODES * 4;
    int*    row_ptr = (int*)p;              p += (size_t)(N_NODES + 16) * 4;
    int*    cursor  = (int*)p;              p += (size_t)N_NODES * 4;
    int*    excl    = (int*)p;              p += (size_t)N_NODES * 4;
    int*    bsum    = (int*)p;              p += 512 * 4;
    int*    boff    = (int*)p;              p += 512 * 4;
    int*    slot_of = (int*)p;              p += (size_t)N_NODES * 4;
    int*    cnts    = (int*)p;              p += (size_t)N_NODES * 4;
    int*    batchs  = (int*)p;              p += (size_t)N_NODES * 4;
    int*    hist    = (int*)p;              p += 32 * 4;
    int*    binoff  = (int*)p;              p += 32 * 4;
    int*    bincur  = (int*)p;              p += 32 * 4;

    hipMemsetAsync(d_out, 0, (size_t)NG * 4, stream);
    k_prep<<<512, 256, 0, stream>>>(gru_w_ih, gru_w_hh, root_w, lin1_w, gru_b_ih, gru_b_hh,
                                    nn1_w, nn1_b, Wb, B2b, w1b, cnt, hist, bincur);
    k_degree<<<N_EDGES / 256, 256, 0, stream>>>(ei, cnt);
    k_hist<<<N_NODES / 256, 256, 0, stream>>>(cnt, hist);
    k_binoff<<<1, 64, 0, stream>>>(hist, binoff);
    k_permute<<<N_NODES / 256, 256, 0, stream>>>(cnt, binoff, bincur, batch,
                                                 slot_of, cnts, invs, batchs);
    k_scanA<<<N_NODES / 256, 256, 0, stream>>>(cnts, excl, bsum);
    k_scanB<<<1, 256, 0, stream>>>(bsum, boff);
    k_scanC<<<N_NODES / 256, 256, 0, stream>>>(excl, boff, row_ptr, cursor);
    k_scatter<<<N_EDGES / 256, 256, 0, stream>>>(ei, edge_attr, slot_of, cursor, csr_pk);
    k_init<<<N_NODES / 16, 256, 0, stream>>>(x, lin0_w, lin0_b, slot_of, h);
    k_lin1<<<N_NODES / 64, 256, 0, stream>>>(h, lin1_w, lin1_b, out1A);

    for (int it = 0; it < N_ITERS; ++it) {
        int j = it >> 1;   // GRU index (NL2 = 2)
        const __bf16* o_in = (it & 1) ? out1B : out1A;
        __bf16*       o_out= (it & 1) ? out1A : out1B;
        k_node<<<N_NODES / 128, 512, 0, stream>>>(o_in, o_out, csr_pk, row_ptr, invs,
                                                  h, Wb + (size_t)j * 40 * 512, B2b, w1b,
                                                  conv_b, gru_b_ih + (size_t)j * 192, lin1_b,
                                                  batchs, lin2_w, out, it == N_ITERS - 1 ? 1 : 0);
    }
}

// Round 23
// 327.857 us; speedup vs baseline: 4.3353x; 1.0062x over previous
//
#include <hip/hip_runtime.h>
#include <hip/hip_bf16.h>

#define N_NODES 131072
#define N_EDGES 524288
#define F_IN 16
#define DIM 64
#define DNN 16
#define BK 4
#define NG 8192
#define N_ITERS 8   // NL1*NL2

typedef __bf16 bf16x8 __attribute__((ext_vector_type(8)));
typedef __bf16 bf16x4 __attribute__((ext_vector_type(4)));
typedef float f32x4 __attribute__((ext_vector_type(4)));

#define FMA4(A_, S_, W_) { (A_).x = fmaf((S_), (W_).x, (A_).x); (A_).y = fmaf((S_), (W_).y, (A_).y); \
                           (A_).z = fmaf((S_), (W_).z, (A_).z); (A_).w = fmaf((S_), (W_).w, (A_).w); }

__device__ __forceinline__ unsigned bf16_rne(float f) {
    unsigned u = __float_as_uint(f);
    return (u + 0x7fffu + ((u >> 16) & 1u)) >> 16;
}

// ---------------- degree (int, node-indexed) ----------------
__global__ __launch_bounds__(256) void k_degree(const int* __restrict__ ei, int* __restrict__ cnt) {
    int e = blockIdx.x * 256 + threadIdx.x;
    atomicAdd(&cnt[ei[N_EDGES + e]], 1);
}

// ---------------- degree-descending counting sort (two-level histogram) ----------------
__global__ __launch_bounds__(256) void k_hist(const int* __restrict__ cnt, int* __restrict__ hist) {
    __shared__ int lh[32];
    int tid = threadIdx.x;
    if (tid < 32) lh[tid] = 0;
    __syncthreads();
    int n = blockIdx.x * 256 + tid;
    int key = 31 - min(cnt[n], 31);            // slot ascending == degree descending
    atomicAdd(&lh[key], 1);
    __syncthreads();
    if (tid < 32 && lh[tid]) atomicAdd(&hist[tid], lh[tid]);
}

__global__ __launch_bounds__(64) void k_binoff(const int* __restrict__ hist, int* __restrict__ binoff) {
    if (threadIdx.x == 0) {
        int acc = 0;
#pragma unroll
        for (int i = 0; i < 32; ++i) { binoff[i] = acc; acc += hist[i]; }
    }
}

// slot_of[node]; per-slot arrays: cnts, invs, batchs
__global__ __launch_bounds__(256) void k_permute(const int* __restrict__ cnt, const int* __restrict__ binoff,
                                                 int* __restrict__ bincur, const int* __restrict__ batch,
                                                 int* __restrict__ slot_of, int* __restrict__ cnts,
                                                 float* __restrict__ invs, int* __restrict__ batchs) {
    __shared__ int lh[32], lbase[32];
    int tid = threadIdx.x;
    if (tid < 32) lh[tid] = 0;
    __syncthreads();
    int n = blockIdx.x * 256 + tid;
    int deg = cnt[n];
    int key = 31 - min(deg, 31);
    int myrank = atomicAdd(&lh[key], 1);       // LDS atomic: block-local rank
    __syncthreads();
    if (tid < 32) lbase[tid] = lh[tid] ? atomicAdd(&bincur[tid], lh[tid]) : 0;
    __syncthreads();
    int slot = binoff[key] + lbase[key] + myrank;
    slot_of[n] = slot;
    cnts[slot] = deg;
    invs[slot] = 1.0f / (float)max(deg, 1);
    batchs[slot] = batch[n];
}

// ---------------- CSR scan (slot-indexed) ----------------
__global__ __launch_bounds__(256) void k_scanA(const int* __restrict__ cnt, int* __restrict__ excl,
                                               int* __restrict__ bsum) {
    __shared__ int a[256], b[256];
    int t = threadIdx.x, gid = blockIdx.x * 256 + t;
    int c = cnt[gid];
    a[t] = c; __syncthreads();
    int *s = a, *d = b;
#pragma unroll
    for (int off = 1; off < 256; off <<= 1) {
        d[t] = s[t] + (t >= off ? s[t - off] : 0);
        __syncthreads();
        int* tmp = s; s = d; d = tmp;
    }
    excl[gid] = s[t] - c;
    if (t == 255) bsum[blockIdx.x] = s[255];
}

__global__ __launch_bounds__(256) void k_scanB(const int* __restrict__ bsum, int* __restrict__ boff) {
    __shared__ int a[512], b[512];
    int t = threadIdx.x;
    a[t] = bsum[t]; a[t + 256] = bsum[t + 256];
    __syncthreads();
    int *s = a, *d = b;
#pragma unroll
    for (int off = 1; off < 512; off <<= 1) {
        d[t] = s[t] + (t >= off ? s[t - off] : 0);
        int i2 = t + 256;
        d[i2] = s[i2] + (i2 >= off ? s[i2 - off] : 0);
        __syncthreads();
        int* tmp = s; s = d; d = tmp;
    }
    boff[t] = t ? s[t - 1] : 0;
    boff[t + 256] = s[t + 255];
}

__global__ __launch_bounds__(256) void k_scanC(const int* __restrict__ excl, const int* __restrict__ boff,
                                               int* __restrict__ row_ptr, int* __restrict__ cursor) {
    int gid = blockIdx.x * 256 + threadIdx.x;
    int v = excl[gid] + boff[gid >> 8];
    row_ptr[gid] = v;
    cursor[gid] = v;
    if (gid == 0) row_ptr[N_NODES] = N_EDGES;
}

// packed edge record (slot space): {src_slot, bf16(a0,a1), bf16(a2,a3), 0}
__global__ __launch_bounds__(256) void k_scatter(const int* __restrict__ ei, const float* __restrict__ ea,
                                                 const int* __restrict__ slot_of,
                                                 int* __restrict__ cursor, int4* __restrict__ csr_pk) {
    int e = blockIdx.x * 256 + threadIdx.x;
    int ds = slot_of[ei[N_EDGES + e]];
    int pos = atomicAdd(&cursor[ds], 1);
    float4 a = ((const float4*)ea)[e];
    unsigned a01 = bf16_rne(a.x) | (bf16_rne(a.y) << 16);
    unsigned a23 = bf16_rne(a.z) | (bf16_rne(a.w) << 16);
    csr_pk[pos] = make_int4(slot_of[ei[e]], (int)a01, (int)a23, 0);
}

// ---------------- prep: bf16 B-fragment weight tiles + zero cnt/hist/bincur ----------------
#define WB_SZ (4 * 40 * 512)
__global__ __launch_bounds__(256) void k_prep(const float* __restrict__ wih, const float* __restrict__ whh,
                                              const float* __restrict__ rw, const float* __restrict__ w1,
                                              const float* __restrict__ bih, const float* __restrict__ bhh,
                                              const float* __restrict__ nn1w, const float* __restrict__ nn1b,
                                              __bf16* __restrict__ Wb, __bf16* __restrict__ B2b,
                                              __bf16* __restrict__ w1b, int* __restrict__ cnt,
                                              int* __restrict__ hist, int* __restrict__ bincur) {
    int idx = blockIdx.x * 256 + threadIdx.x;
    if (idx < N_NODES) cnt[idx] = 0;           // grid = 512 blocks covers all
    if (idx < 32) { hist[idx] = 0; bincur[idx] = 0; }
    if (idx < WB_SZ) {
        int j = idx / 20480, r = idx % 20480;
        int t = r >> 9, e = r & 511;
        int jj = e & 7, c16 = (e >> 3) & 15, kq = e >> 7;
        int ct, kk; bool nih = false;
        if (t < 36) { ct = t / 3; kk = t % 3; } else { ct = 8 + (t - 36); kk = 0; nih = true; }
        int k = kk * 32 + kq * 8 + jj;
        int c = ct * 16 + c16;
        bool ngate = ct >= 8;
        float v = 0.f;
        if (nih) {
            if (k < 16) v = wih[((size_t)j * 192 + c) * 16 + k];
        } else {
            if (k < 16) v = ngate ? 0.f : wih[((size_t)j * 192 + c) * 16 + k];
            else if (k < 80) v = whh[((size_t)j * 192 + c) * 64 + (k - 16)];
            else if (k == 80) v = ngate ? bhh[j * 192 + c] : (bih[j * 192 + c] + bhh[j * 192 + c]);
        }
        Wb[idx] = (__bf16)v;
    } else if (idx < WB_SZ + 1536) {
        int e = idx - WB_SZ;
        int t = e >> 9, ee = e & 511;
        int jj = ee & 7, c16 = (ee >> 3) & 15, kq = ee >> 7;
        int krow = t * 32 + kq * 8 + jj;
        float v;
        if (krow < 16) v = rw[krow * 16 + c16];
        else {
            int i = (krow - 16) >> 4, kk = (krow - 16) & 15;
            v = (i == 0) ? nn1b[kk * 16 + c16] : nn1w[(i - 1) * 256 + kk * 16 + c16];
        }
        B2b[e] = (__bf16)v;
    } else if (idx < WB_SZ + 1536 + 1024) {
        int e = idx - (WB_SZ + 1536);
        int t2 = e >> 9, ee = e & 511;
        int jj = ee & 7, c16 = (ee >> 3) & 15, kq = ee >> 7;
        int k = t2 * 32 + kq * 8 + jj;
        w1b[e] = (__bf16)w1[k * 16 + c16];
    }
}

// ---------------- fused init: h[slot] = relu(x@w0+b0) ; out1[slot] = h@w1+b1 ----------------
__global__ __launch_bounds__(256) void k_init(const float* __restrict__ x, const float* __restrict__ w0,
                                              const float* __restrict__ b0, const float* __restrict__ w1,
                                              const float* __restrict__ b1, const int* __restrict__ slot_of,
                                              __bf16* __restrict__ h, __bf16* __restrict__ out1) {
    __shared__ float s_w[F_IN * DIM];
    __shared__ float s_h[64 * 68];
    __shared__ int s_slot[64];
    int tid = threadIdx.x;
    int nb = blockIdx.x * 64;
    for (int i = tid; i < F_IN * DIM; i += 256) s_w[i] = w0[i];
    if (tid < 64) s_slot[tid] = slot_of[nb + tid];
    __syncthreads();
    const float4* w4 = (const float4*)s_w;
#pragma unroll
    for (int rep = 0; rep < 4; ++rep) {
        int nl = rep * 16 + (tid >> 4);
        int c4 = tid & 15;
        const float4* xp = (const float4*)(x + (size_t)(nb + nl) * F_IN);
        float4 x0 = xp[0], x1 = xp[1], x2 = xp[2], x3 = xp[3];
        float xa[16] = {x0.x, x0.y, x0.z, x0.w, x1.x, x1.y, x1.z, x1.w,
                        x2.x, x2.y, x2.z, x2.w, x3.x, x3.y, x3.z, x3.w};
        float4 acc = ((const float4*)b0)[c4];
#pragma unroll
        for (int k = 0; k < 16; ++k) {
            float4 wv = w4[k * 16 + c4];
            FMA4(acc, xa[k], wv);
        }
        acc.x = fmaxf(acc.x, 0.f); acc.y = fmaxf(acc.y, 0.f);
        acc.z = fmaxf(acc.z, 0.f); acc.w = fmaxf(acc.w, 0.f);
        *(float4*)&s_h[nl * 68 + c4 * 4] = acc;
        bf16x4 hv;
        hv[0] = (__bf16)acc.x; hv[1] = (__bf16)acc.y; hv[2] = (__bf16)acc.z; hv[3] = (__bf16)acc.w;
        *(bf16x4*)&h[(size_t)s_slot[nl] * DIM + c4 * 4] = hv;
    }
    __syncthreads();
    int ct = tid & 15;
    float wcol[64];
#pragma unroll
    for (int q = 0; q < 64; ++q) wcol[q] = w1[q * 16 + ct];
    float bias = b1[ct];
    int ng = tid >> 4;
#pragma unroll
    for (int rep = 0; rep < 4; ++rep) {
        int nl = ng + 16 * rep;
        float acc = bias;
#pragma unroll
        for (int q4 = 0; q4 < 16; ++q4) {
            float4 hv = *(const float4*)&s_h[nl * 68 + q4 * 4];
            acc = fmaf(hv.x, wcol[4 * q4 + 0], acc);
            acc = fmaf(hv.y, wcol[4 * q4 + 1], acc);
            acc = fmaf(hv.z, wcol[4 * q4 + 2], acc);
            acc = fmaf(hv.w, wcol[4 * q4 + 3], acc);
        }
        out1[(size_t)s_slot[nl] * 16 + ct] = (__bf16)acc;
    }
}

// ---------------- node v16: 4-deep pipelined gather + rcp epilogue + MFMA GRU ----------------
// vs v15: xv prefetched 2 rounds ahead (pk 3 ahead). Extra regs live only in
// the gather phase (arch), staying under the MFMA phase's combined peak ->
// occupancy cap (4 waves/SIMD) unchanged.
__attribute__((amdgpu_waves_per_eu(2, 4)))
__global__ __launch_bounds__(512) void k_node(
    const __bf16* __restrict__ out1_in, __bf16* __restrict__ out1_out,
    const int4* __restrict__ csr_pk,
    const int* __restrict__ row_ptr, const float* __restrict__ invs,
    __bf16* __restrict__ h, const __bf16* __restrict__ Wb, const __bf16* __restrict__ B2b,
    const __bf16* __restrict__ w1b, const float* __restrict__ conv_b,
    const float* __restrict__ bih, const float* __restrict__ lin1_b,
    const int* __restrict__ batchs, const float* __restrict__ lin2_w,
    float* __restrict__ out, int do_final)
{
    __shared__ __align__(16) __bf16 s_X[128 * 104];  // 26624 B
    __shared__ __align__(16) __bf16 s_W[40 * 512];   // 40960 B
    __shared__ __align__(16) __bf16 s_B2[3 * 512];   //  3072 B
    __shared__ __align__(16) __bf16 s_w1[1024];      //  2048 B  (total 72704)
    int tid = threadIdx.x;
    int nb = blockIdx.x * 128;
    int lane = tid & 63, w = tid >> 6;               // w = 0..7
    int c16 = lane & 15, lq = lane >> 4;
    int nwb = nb + w * 16;
    int xrow = w * 16;

    // cooperative staging of weight tiles (512 threads)
    {
        const float4* src = (const float4*)Wb;
        float4* dst = (float4*)s_W;
#pragma unroll
        for (int i = 0; i < 5; ++i) dst[tid + 512 * i] = src[tid + 512 * i];
        if (tid < 192) ((float4*)s_B2)[tid] = ((const float4*)B2b)[tid];
        else if (tid < 320) ((float4*)s_w1)[tid - 192] = ((const float4*)w1b)[tid - 192];
    }
    // own out1 row -> X2[.][0..15]  (wave-private rows)
    {
        int n = lane >> 2, k4 = lane & 3;
        bf16x4 v = *(const bf16x4*)&out1_in[(size_t)(nwb + n) * 16 + k4 * 4];
        *(bf16x4*)&s_X[(xrow + n) * 104 + k4 * 4] = v;
    }
    __syncthreads();   // the ONLY block-wide barrier (covers s_W/s_B2/s_w1)

    // gather: wave-private, 4-deep pipelined. group gi = lane>>4, slots nwb+gi*4+r
    {
        int gi = lane >> 4, k = lane & 15;
        int e0[4], dr[4];
        int4 pk0[4], pk1[4], pk2[4];
        float xv0[4], xv1[4];
        float S0[4] = {0.f,0.f,0.f,0.f}, S1[4] = {0.f,0.f,0.f,0.f}, S2[4] = {0.f,0.f,0.f,0.f},
              S3[4] = {0.f,0.f,0.f,0.f}, S4[4] = {0.f,0.f,0.f,0.f};
        int rounds = 0;
#pragma unroll
        for (int r = 0; r < 4; ++r) {
            int n = nwb + gi * 4 + r;
            e0[r] = row_ptr[n];
            dr[r] = row_ptr[n + 1] - e0[r];
            rounds = max(rounds, dr[r]);
            pk0[r] = csr_pk[min(e0[r], N_EDGES - 1)];
        }
#pragma unroll
        for (int r = 0; r < 4; ++r) pk1[r] = csr_pk[min(e0[r] + 1, N_EDGES - 1)];
#pragma unroll
        for (int r = 0; r < 4; ++r) pk2[r] = csr_pk[min(e0[r] + 2, N_EDGES - 1)];
#pragma unroll
        for (int r = 0; r < 4; ++r) xv0[r] = (float)out1_in[(size_t)(pk0[r].x & 0xFFFFF) * 16 + k];
#pragma unroll
        for (int r = 0; r < 4; ++r) xv1[r] = (float)out1_in[(size_t)(pk1[r].x & 0xFFFFF) * 16 + k];
        for (int t = 0; t < rounds; ++t) {
            int4 pk3[4]; float xv2[4];
#pragma unroll
            for (int r = 0; r < 4; ++r)
                pk3[r] = csr_pk[min(e0[r] + t + 3, N_EDGES - 1)];
#pragma unroll
            for (int r = 0; r < 4; ++r)
                xv2[r] = (float)out1_in[(size_t)(pk2[r].x & 0xFFFFF) * 16 + k];
#pragma unroll
            for (int r = 0; r < 4; ++r) {
                float xm = (t < dr[r]) ? xv0[r] : 0.0f;
                float a0 = __uint_as_float(((unsigned)pk0[r].y) << 16);
                float a1 = __uint_as_float(((unsigned)pk0[r].y) & 0xffff0000u);
                float a2 = __uint_as_float(((unsigned)pk0[r].z) << 16);
                float a3 = __uint_as_float(((unsigned)pk0[r].z) & 0xffff0000u);
                S0[r] += xm;
                S1[r] = fmaf(a0, xm, S1[r]);
                S2[r] = fmaf(a1, xm, S2[r]);
                S3[r] = fmaf(a2, xm, S3[r]);
                S4[r] = fmaf(a3, xm, S4[r]);
                pk0[r] = pk1[r]; pk1[r] = pk2[r]; pk2[r] = pk3[r];
                xv0[r] = xv1[r]; xv1[r] = xv2[r];
            }
        }
#pragma unroll
        for (int r = 0; r < 4; ++r) {
            int nl = xrow + gi * 4 + r;
            float inv = invs[nwb + gi * 4 + r];
            __bf16* p = &s_X[nl * 104];
            p[16 + k] = (__bf16)(S0[r] * inv);
            p[32 + k] = (__bf16)(S1[r] * inv);
            p[48 + k] = (__bf16)(S2[r] * inv);
            p[64 + k] = (__bf16)(S3[r] * inv);
            p[80 + k] = (__bf16)(S4[r] * inv);
        }
    }
    // no barrier: s_X rows are wave-private; same-wave DS ops are in program order

    // phase 2: o2 = X2 @ B2 + conv_b (K=96)
    float cb = conv_b[c16];
    f32x4 co2 = (f32x4){cb, cb, cb, cb};
#pragma unroll
    for (int kk = 0; kk < 3; ++kk) {
        bf16x8 a = *(const bf16x8*)&s_X[(xrow + c16) * 104 + kk * 32 + lq * 8];
        bf16x8 b = *(const bf16x8*)&s_B2[kk * 512 + lane * 8];
        co2 = __builtin_amdgcn_mfma_f32_16x16x32_bf16(a, b, co2, 0, 0, 0);
    }

    // phase 3a: rebuild X = [o2(16) | h(64) | 1 | 0..]  (wave-own rows)
#pragma unroll
    for (int jr = 0; jr < 4; ++jr)
        s_X[(xrow + 4 * lq + jr) * 104 + c16] = (__bf16)co2[jr];
    {
        const bf16x8* hsrc = (const bf16x8*)(h + (size_t)nwb * 64);
#pragma unroll
        for (int ii = 0; ii < 2; ++ii) {
            int idx = lane + 64 * ii;
            int n = idx >> 3, d8 = idx & 7;
            bf16x8 v = hsrc[idx];
            *(bf16x8*)&s_X[(xrow + n) * 104 + 16 + d8 * 8] = v;
        }
    }
    {
        int n = lane >> 2, c0 = 80 + (lane & 3) * 4;
#pragma unroll
        for (int q = 0; q < 4; ++q)
            s_X[(xrow + n) * 104 + c0 + q] = (c0 + q == 80) ? (__bf16)1.0f : (__bf16)0.0f;
    }

    // phase 3b: gates GEMM
    f32x4 acc[12], ani4[4];
#pragma unroll
    for (int i = 0; i < 12; ++i) acc[i] = (f32x4){0.f, 0.f, 0.f, 0.f};
#pragma unroll
    for (int i = 0; i < 4; ++i) ani4[i] = (f32x4){0.f, 0.f, 0.f, 0.f};
    bf16x8 af[3];
#pragma unroll
    for (int kk = 0; kk < 3; ++kk)
        af[kk] = *(const bf16x8*)&s_X[(xrow + c16) * 104 + kk * 32 + lq * 8];
#pragma unroll
    for (int ct = 0; ct < 12; ++ct) {
#pragma unroll
        for (int kk = 0; kk < 3; ++kk) {
            bf16x8 bf = *(const bf16x8*)&s_W[(ct * 3 + kk) * 512 + lane * 8];
            acc[ct] = __builtin_amdgcn_mfma_f32_16x16x32_bf16(af[kk], bf, acc[ct], 0, 0, 0);
        }
    }
#pragma unroll
    for (int ct8 = 0; ct8 < 4; ++ct8) {
        bf16x8 bf = *(const bf16x8*)&s_W[(36 + ct8) * 512 + lane * 8];
        ani4[ct8] = __builtin_amdgcn_mfma_f32_16x16x32_bf16(af[0], bf, ani4[ct8], 0, 0, 0);
    }

    // GRU epilogue (hold from s_X bf16); fast rcp for sigmoid/tanh
    float hn[4][4];
#pragma unroll
    for (int ct = 0; ct < 4; ++ct) {
        float bni = bih[128 + ct * 16 + c16];
#pragma unroll
        for (int jr = 0; jr < 4; ++jr) {
            float hold = (float)s_X[(xrow + 4 * lq + jr) * 104 + 16 + ct * 16 + c16];
            float rr = __builtin_amdgcn_rcpf(1.f + __expf(-acc[ct][jr]));
            float zz = __builtin_amdgcn_rcpf(1.f + __expf(-acc[4 + ct][jr]));
            float xx = fmaf(rr, acc[8 + ct][jr], ani4[ct][jr] + bni);
            float ax = fabsf(xx);
            float ee = __expf(-2.f * ax);
            float ncv = __builtin_copysignf((1.f - ee) * __builtin_amdgcn_rcpf(1.f + ee), xx);
            hn[ct][jr] = fmaf(zz, hold - ncv, ncv);
        }
    }
    // write h_new into s_X (same-wave DS order), then coalesced bf16 writeback to h
#pragma unroll
    for (int ct = 0; ct < 4; ++ct)
#pragma unroll
        for (int jr = 0; jr < 4; ++jr)
            s_X[(xrow + 4 * lq + jr) * 104 + 16 + ct * 16 + c16] = (__bf16)hn[ct][jr];
    {
        bf16x8* hdst = (bf16x8*)(h + (size_t)nwb * 64);
#pragma unroll
        for (int ii = 0; ii < 2; ++ii) {
            int idx = lane + 64 * ii;
            int n = idx >> 3, d8 = idx & 7;
            bf16x8 v = *(const bf16x8*)&s_X[(xrow + n) * 104 + 16 + d8 * 8];
            hdst[idx] = v;
        }
    }

    if (!do_final) {
        // fused lin1 -> out1_out (bf16)
        f32x4 o1acc = (f32x4){0.f, 0.f, 0.f, 0.f};
#pragma unroll
        for (int kk = 0; kk < 2; ++kk) {
            bf16x8 a = *(const bf16x8*)&s_X[(xrow + c16) * 104 + 16 + kk * 32 + lq * 8];
            bf16x8 b = *(const bf16x8*)&s_w1[kk * 512 + lane * 8];
            o1acc = __builtin_amdgcn_mfma_f32_16x16x32_bf16(a, b, o1acc, 0, 0, 0);
        }
        float lb = lin1_b[c16];
#pragma unroll
        for (int jr = 0; jr < 4; ++jr) {
            int node = nwb + 4 * lq + jr;
            out1_out[(size_t)node * 16 + c16] = (__bf16)(o1acc[jr] + lb);
        }
    } else {
        // fused final: y = h_new @ lin2_w ; atomicAdd into out[batchs]
        float w2v[4];
#pragma unroll
        for (int ct = 0; ct < 4; ++ct) w2v[ct] = lin2_w[ct * 16 + c16];
#pragma unroll
        for (int jr = 0; jr < 4; ++jr) {
            float part = hn[0][jr] * w2v[0];
            part = fmaf(hn[1][jr], w2v[1], part);
            part = fmaf(hn[2][jr], w2v[2], part);
            part = fmaf(hn[3][jr], w2v[3], part);
#pragma unroll
            for (int off = 8; off > 0; off >>= 1) part += __shfl_xor(part, off, 64);
            if (c16 == 0) {
                int node = nwb + 4 * lq + jr;
                atomicAdd(&out[batchs[node]], part);
            }
        }
    }
}

extern "C" void kernel_launch(void* const* d_in, const int* in_sizes, int n_in,
                              void* d_out, int out_size, void* d_ws, size_t ws_size,
                              hipStream_t stream) {
    const float* x        = (const float*)d_in[0];
    const float* edge_attr= (const float*)d_in[1];
    const float* lin0_w   = (const float*)d_in[2];
    const float* lin0_b   = (const float*)d_in[3];
    const float* nn1_w    = (const float*)d_in[4];
    const float* nn1_b    = (const float*)d_in[5];
    const float* root_w   = (const float*)d_in[6];
    const float* conv_b   = (const float*)d_in[7];
    const float* gru_w_ih = (const float*)d_in[8];
    const float* gru_w_hh = (const float*)d_in[9];
    const float* gru_b_ih = (const float*)d_in[10];
    const float* gru_b_hh = (const float*)d_in[11];
    const float* lin1_w   = (const float*)d_in[12];
    const float* lin1_b   = (const float*)d_in[13];
    const float* lin2_w   = (const float*)d_in[14];
    const int*   ei       = (const int*)d_in[15];
    const int*   batch    = (const int*)d_in[16];
    float* out = (float*)d_out;

    char* p = (char*)d_ws;
    __bf16* h       = (__bf16*)p;           p += (size_t)N_NODES * DIM * 2;
    __bf16* out1A   = (__bf16*)p;           p += (size_t)N_NODES * DNN * 2;
    __bf16* out1B   = (__bf16*)p;           p += (size_t)N_NODES * DNN * 2;
    int4*   csr_pk  = (int4*)p;             p += (size_t)N_EDGES * 16;
    __bf16* Wb      = (__bf16*)p;           p += (size_t)WB_SZ * 2;
    __bf16* B2b     = (__bf16*)p;           p += 1536 * 2;
    __bf16* w1b     = (__bf16*)p;           p += 1024 * 2;
    int*    cnt     = (int*)p;              p += (size_t)N_NODES * 4;
    float*  invs    = (float*)p;            p += (size_t)N_NODES * 4;
    int*    row_ptr = (int*)p;              p += (size_t)(N_NODES + 16) * 4;
    int*    cursor  = (int*)p;              p += (size_t)N_NODES * 4;
    int*    excl    = (int*)p;              p += (size_t)N_NODES * 4;
    int*    bsum    = (int*)p;              p += 512 * 4;
    int*    boff    = (int*)p;              p += 512 * 4;
    int*    slot_of = (int*)p;              p += (size_t)N_NODES * 4;
    int*    cnts    = (int*)p;              p += (size_t)N_NODES * 4;
    int*    batchs  = (int*)p;              p += (size_t)N_NODES * 4;
    int*    hist    = (int*)p;              p += 32 * 4;
    int*    binoff  = (int*)p;              p += 32 * 4;
    int*    bincur  = (int*)p;              p += 32 * 4;

    hipMemsetAsync(d_out, 0, (size_t)NG * 4, stream);
    k_prep<<<512, 256, 0, stream>>>(gru_w_ih, gru_w_hh, root_w, lin1_w, gru_b_ih, gru_b_hh,
                                    nn1_w, nn1_b, Wb, B2b, w1b, cnt, hist, bincur);
    k_degree<<<N_EDGES / 256, 256, 0, stream>>>(ei, cnt);
    k_hist<<<N_NODES / 256, 256, 0, stream>>>(cnt, hist);
    k_binoff<<<1, 64, 0, stream>>>(hist, binoff);
    k_permute<<<N_NODES / 256, 256, 0, stream>>>(cnt, binoff, bincur, batch,
                                                 slot_of, cnts, invs, batchs);
    k_scanA<<<N_NODES / 256, 256, 0, stream>>>(cnts, excl, bsum);
    k_scanB<<<1, 256, 0, stream>>>(bsum, boff);
    k_scanC<<<N_NODES / 256, 256, 0, stream>>>(excl, boff, row_ptr, cursor);
    k_scatter<<<N_EDGES / 256, 256, 0, stream>>>(ei, edge_attr, slot_of, cursor, csr_pk);
    k_init<<<N_NODES / 64, 256, 0, stream>>>(x, lin0_w, lin0_b, lin1_w, lin1_b, slot_of, h, out1A);

    for (int it = 0; it < N_ITERS; ++it) {
        int j = it >> 1;   // GRU index (NL2 = 2)
        const __bf16* o_in = (it & 1) ? out1B : out1A;
        __bf16*       o_out= (it & 1) ? out1A : out1B;
        k_node<<<N_NODES / 128, 512, 0, stream>>>(o_in, o_out, csr_pk, row_ptr, invs,
                                                  h, Wb + (size_t)j * 40 * 512, B2b, w1b,
                                                  conv_b, gru_b_ih + (size_t)j * 192, lin1_b,
                                                  batchs, lin2_w, out, it == N_ITERS - 1 ? 1 : 0);
    }
}